// Round 4
// baseline (25646.478 us; speedup 1.0000x reference)
//
#include <hip/hip_runtime.h>
#include <cstddef>

typedef short short8 __attribute__((ext_vector_type(8)));
typedef float floatx4 __attribute__((ext_vector_type(4)));

// ---- bf16 helpers (round-to-nearest-even) ---------------------------------
__device__ __forceinline__ unsigned short f2bf(float f) {
    unsigned u = __float_as_uint(f);
    u += 0x7FFFu + ((u >> 16) & 1u);
    return (unsigned short)(u >> 16);
}
__device__ __forceinline__ float bf2f(unsigned short h) {
    return __uint_as_float((unsigned)h << 16);
}

// ---------------------------------------------------------------------------
// Fused conv1(3->64,s1) + relu + conv2(64->128,s2) + relu.  fp32 (VQ fidelity)
// ---------------------------------------------------------------------------
__global__ __launch_bounds__(256)
void fused_conv12_kernel(const float* __restrict__ x,   // [16,3,256,256]
                         const float* __restrict__ w1,  // [64,3,3,3]
                         const float* __restrict__ b1,
                         const float* __restrict__ w2,  // [128,64,3,3]
                         const float* __restrict__ b2,
                         float* __restrict__ out)       // [16,128,128,128]
{
    __shared__ float s_x[3][11][67];
    __shared__ float s_w1[64][28];
    __shared__ float s_h1[8][9][65];
    __shared__ float s_w2[72][65];

    const int tid = threadIdx.x;
    const int tx = tid & 15, ty = tid >> 4;
    const int tileX = blockIdx.x & 3;
    const int tileY = blockIdx.x >> 2;
    const int x0 = tileX * 32, y0 = tileY * 4;
    const int co0 = blockIdx.y * 64;
    const int n = blockIdx.z;
    const float* xN = x + (size_t)n * 3 * 65536;

    const int gy0 = 2 * y0 - 2, gx0 = 2 * x0 - 2;
    const int hy0 = 2 * y0 - 1, hx0 = 2 * x0 - 1;

    for (int e = tid; e < 3 * 11 * 67; e += 256) {
        int c = e / 737, r = e % 737;
        int yy = r / 67, xx = r % 67;
        int gy = gy0 + yy, gx = gx0 + xx;
        float v = 0.f;
        if ((unsigned)gy < 256u && (unsigned)gx < 256u)
            v = xN[(size_t)c * 65536 + gy * 256 + gx];
        s_x[c][yy][xx] = v;
    }
    for (int e = tid; e < 64 * 27; e += 256)
        s_w1[e / 27][e % 27] = w1[e];

    float acc[4][4][2] = {};

    for (int ci0 = 0; ci0 < 64; ci0 += 8) {
        __syncthreads();
        for (int e = tid; e < 8 * 9 * 65; e += 256) {
            int m = e / 585, r = e % 585;
            int ly = r / 65, lx = r % 65;
            float v = 0.f;
            if ((unsigned)(hy0 + ly) < 256u && (unsigned)(hx0 + lx) < 256u) {
                const int gm = ci0 + m;
                float s = b1[gm];
#pragma unroll
                for (int c = 0; c < 3; c++)
#pragma unroll
                    for (int ky = 0; ky < 3; ky++)
#pragma unroll
                        for (int kx = 0; kx < 3; kx++)
                            s += s_w1[gm][c * 9 + ky * 3 + kx] * s_x[c][ly + ky][lx + kx];
                v = fmaxf(s, 0.f);
            }
            s_h1[m][ly][lx] = v;
        }
        for (int e = tid; e < 64 * 72; e += 256) {
            int co = e / 72, r = e % 72;
            s_w2[r][co] = w2[(size_t)(co0 + co) * 576 + ci0 * 9 + r];
        }
        __syncthreads();
#pragma unroll
        for (int ci = 0; ci < 8; ++ci) {
#pragma unroll
            for (int k = 0; k < 9; ++k) {
                const int ky = k / 3, kx = k % 3;
                float wv[4];
#pragma unroll
                for (int i = 0; i < 4; i++) wv[i] = s_w2[ci * 9 + k][ty * 4 + i];
                float iv[4][2];
#pragma unroll
                for (int j = 0; j < 4; j++) {
                    iv[j][0] = s_h1[ci][j * 2 + ky][(tx * 2 + 0) * 2 + kx];
                    iv[j][1] = s_h1[ci][j * 2 + ky][(tx * 2 + 1) * 2 + kx];
                }
#pragma unroll
                for (int i = 0; i < 4; i++)
#pragma unroll
                    for (int j = 0; j < 4; j++) {
                        acc[i][j][0] += wv[i] * iv[j][0];
                        acc[i][j][1] += wv[i] * iv[j][1];
                    }
            }
        }
    }
#pragma unroll
    for (int i = 0; i < 4; i++) {
        const int co = co0 + ty * 4 + i;
        const float b = b2[co];
#pragma unroll
        for (int j = 0; j < 4; j++) {
            float2 v;
            v.x = fmaxf(acc[i][j][0] + b, 0.f);
            v.y = fmaxf(acc[i][j][1] + b, 0.f);
            *(float2*)(out + (size_t)((n * 128 + co) * 128 + (y0 + j)) * 128 + x0 + tx * 2) = v;
        }
    }
}

// ---------------------------------------------------------------------------
// 3x3 conv s=2 fp32 (encoder conv3/conv4)
// ---------------------------------------------------------------------------
template<int TIC, bool RELU>
__global__ __launch_bounds__(256)
void conv3x3s2_kernel(const float* __restrict__ in, const float* __restrict__ w,
                      const float* __restrict__ bias, float* __restrict__ out,
                      int CIN, int COUT, int IH, int IW, int OH, int OW)
{
    constexpr int IYT = 9, IXT = 65;
    __shared__ float s_in[TIC][IYT][IXT];
    __shared__ float s_w[TIC * 9][65];

    const int tid = threadIdx.x;
    const int tx = tid & 15;
    const int ty = tid >> 4;

    const int ntx = OW / 32;
    const int tileX = blockIdx.x % ntx;
    const int tileY = blockIdx.x / ntx;
    const int x0 = tileX * 32;
    const int y0 = tileY * 4;
    const int co0 = blockIdx.y * 64;
    const int n = blockIdx.z;

    const float* inN = in + (size_t)n * CIN * IH * IW;

    float acc[4][4][2] = {};

    const int iy0 = y0 * 2 - 1;
    const int ix0 = x0 * 2 - 1;

    for (int c0 = 0; c0 < CIN; c0 += TIC) {
        for (int e = tid; e < TIC * IYT * IXT; e += 256) {
            int ci = e / (IYT * IXT);
            int r  = e % (IYT * IXT);
            int yy = r / IXT, xx = r % IXT;
            int gy = iy0 + yy, gx = ix0 + xx;
            float v = 0.f;
            if ((unsigned)gy < (unsigned)IH && (unsigned)gx < (unsigned)IW)
                v = inN[(size_t)(c0 + ci) * IH * IW + (size_t)gy * IW + gx];
            s_in[ci][yy][xx] = v;
        }
        for (int e = tid; e < 64 * TIC * 9; e += 256) {
            int co = e / (TIC * 9);
            int r  = e % (TIC * 9);
            s_w[r][co] = w[(size_t)(co0 + co) * CIN * 9 + (size_t)c0 * 9 + r];
        }
        __syncthreads();
#pragma unroll
        for (int ci = 0; ci < TIC; ++ci) {
#pragma unroll
            for (int k = 0; k < 9; ++k) {
                const int ky = k / 3, kx = k % 3;
                float wv[4];
#pragma unroll
                for (int i = 0; i < 4; i++) wv[i] = s_w[ci * 9 + k][ty * 4 + i];
                float iv[4][2];
#pragma unroll
                for (int j = 0; j < 4; j++) {
                    iv[j][0] = s_in[ci][j * 2 + ky][(tx * 2 + 0) * 2 + kx];
                    iv[j][1] = s_in[ci][j * 2 + ky][(tx * 2 + 1) * 2 + kx];
                }
#pragma unroll
                for (int i = 0; i < 4; i++)
#pragma unroll
                    for (int j = 0; j < 4; j++) {
                        acc[i][j][0] += wv[i] * iv[j][0];
                        acc[i][j][1] += wv[i] * iv[j][1];
                    }
            }
        }
        __syncthreads();
    }

#pragma unroll
    for (int i = 0; i < 4; i++) {
        const int co = co0 + ty * 4 + i;
        const float b = bias[co];
#pragma unroll
        for (int j = 0; j < 4; j++) {
            float2 v;
            v.x = acc[i][j][0] + b;
            v.y = acc[i][j][1] + b;
            if (RELU) { v.x = fmaxf(v.x, 0.f); v.y = fmaxf(v.y, 0.f); }
            *(float2*)(out + (size_t)((n * COUT + co) * OH + (y0 + j)) * OW + x0 + tx * 2) = v;
        }
    }
}

// ---------------------------------------------------------------------------
__global__ __launch_bounds__(64)
void cnorm_kernel(const float* __restrict__ cb, float* __restrict__ cn)
{
    const int code = blockIdx.x;
    const int t = threadIdx.x;
    const float* row = cb + (size_t)code * 512;
    float s = 0.f;
    for (int i = t; i < 512; i += 64) s += row[i] * row[i];
#pragma unroll
    for (int off = 32; off > 0; off >>= 1) s += __shfl_down(s, off, 64);
    if (t == 0) cn[code] = s;
}

__global__ __launch_bounds__(256)
void init_keys_kernel(unsigned long long* __restrict__ keys)
{
    keys[blockIdx.x * 256 + threadIdx.x] = ~0ull;
}

// ---------------------------------------------------------------------------
// VQ distance GEMM + argmin (fp32 exact).
// Micro-tile rows split {tr*4, 64+tr*4} -> 2-way LDS conflicts (free).
// sred aliased over sA/sB: LDS 17.4 KB.  launch_bounds(256,4) caps VGPR @128.
// ---------------------------------------------------------------------------
__global__ __launch_bounds__(256, 4)
void vq_dist_kernel(const float* __restrict__ z,   // [16,512,32,32]
                    const float* __restrict__ cb,  // [8192,512]
                    const float* __restrict__ cn,
                    unsigned long long* __restrict__ keys) // [16384]
{
    __shared__ __align__(16) char smem[17408];
    float (*sA)[132] = (float (*)[132])smem;                 // [16][132]
    float (*sB)[132] = (float (*)[132])(smem + 16 * 132 * 4);
    unsigned long long (*sred)[17] = (unsigned long long (*)[17])smem;

    const int t = threadIdx.x;
    const int tr = t & 15, tc = t >> 4;
    const int v0 = blockIdx.x * 128;
    const int code0 = blockIdx.y * 128;
    const int n = v0 >> 10;
    const int hw0 = v0 & 1023;
    const float* zN = z + (size_t)n * 512 * 1024;

    float acc[8][8] = {};

    for (int k0 = 0; k0 < 512; k0 += 16) {
        for (int e = t; e < 512; e += 256) {
            int kk = e >> 5;
            int r4 = e & 31;
            const float4 v = *(const float4*)(zN + (size_t)(k0 + kk) * 1024 + hw0 + r4 * 4);
            *(float4*)&sA[kk][r4 * 4] = v;
        }
        for (int e = t; e < 512; e += 256) {
            int code = e >> 2;
            int q = e & 3;
            const float4 v = *(const float4*)(cb + (size_t)(code0 + code) * 512 + k0 + q * 4);
            sB[q * 4 + 0][code] = v.x;
            sB[q * 4 + 1][code] = v.y;
            sB[q * 4 + 2][code] = v.z;
            sB[q * 4 + 3][code] = v.w;
        }
        __syncthreads();
#pragma unroll
        for (int k = 0; k < 16; ++k) {
            float a[8], b[8];
            *(float4*)&a[0] = *(const float4*)&sA[k][tr * 4];
            *(float4*)&a[4] = *(const float4*)&sA[k][64 + tr * 4];
            *(float4*)&b[0] = *(const float4*)&sB[k][tc * 8];
            *(float4*)&b[4] = *(const float4*)&sB[k][tc * 8 + 4];
#pragma unroll
            for (int i = 0; i < 8; i++)
#pragma unroll
                for (int j = 0; j < 8; j++)
                    acc[i][j] += a[i] * b[j];
        }
        __syncthreads();
    }

#pragma unroll
    for (int i = 0; i < 8; i++) {
        float best = 3.0e38f;
        int bj = 0;
#pragma unroll
        for (int j = 0; j < 8; j++) {
            float s = cn[code0 + tc * 8 + j] - 2.0f * acc[i][j];
            if (s < best) { best = s; bj = j; }
        }
        unsigned u = __float_as_uint(best);
        u = (u & 0x80000000u) ? ~u : (u | 0x80000000u);
        unsigned long long key = ((unsigned long long)u << 32) |
                                 (unsigned)(code0 + tc * 8 + bj);
        const int row = (i < 4) ? (tr * 4 + i) : (64 + tr * 4 + (i - 4));
        sred[row][tc] = key;
    }
    __syncthreads();
    if (t < 128) {
        unsigned long long m = sred[t][0];
#pragma unroll
        for (int c = 1; c < 16; c++) {
            unsigned long long v = sred[t][c];
            m = (v < m) ? v : m;
        }
        atomicMin(&keys[v0 + t], m);
    }
}

// ---------------------------------------------------------------------------
// Gather: indices (float) into d_out tail, zq as bf16 NHWC [16,32,32,512].
// ---------------------------------------------------------------------------
__global__ __launch_bounds__(256)
void vq_gather_kernel(const unsigned long long* __restrict__ keys,
                      const float* __restrict__ cb,
                      unsigned short* __restrict__ zq, float* __restrict__ idx_out)
{
    __shared__ int sidx[64];
    const int t = threadIdx.x;
    const int v0 = blockIdx.x * 64;
    if (t < 64) {
        int idx = (int)(keys[v0 + t] & 0xFFFFFFFFull);
        sidx[t] = idx;
        idx_out[v0 + t] = (float)idx;
    }
    __syncthreads();
    const int tv = t >> 2;
    const int q = t & 3;
    const float* crow = cb + (size_t)sidx[tv] * 512;
    unsigned short* zrow = zq + (size_t)(v0 + tv) * 512;
    for (int c = q * 8; c < 512; c += 32) {
        float4 f0 = *(const float4*)(crow + c);
        float4 f1 = *(const float4*)(crow + c + 4);
        short8 h;
        h[0] = (short)f2bf(f0.x); h[1] = (short)f2bf(f0.y);
        h[2] = (short)f2bf(f0.z); h[3] = (short)f2bf(f0.w);
        h[4] = (short)f2bf(f1.x); h[5] = (short)f2bf(f1.y);
        h[6] = (short)f2bf(f1.z); h[7] = (short)f2bf(f1.w);
        *(short8*)(zrow + c) = h;
    }
}

// ---------------------------------------------------------------------------
// Weight prepack: torch [CI][CO][3][3] f32 -> [tap][CO][CI] bf16
// ---------------------------------------------------------------------------
template<int CI, int CO>
__global__ __launch_bounds__(256)
void prepack_kernel(const float* __restrict__ w, unsigned short* __restrict__ wp)
{
    int i = blockIdx.x * 256 + threadIdx.x;
    if (i >= 9 * CO * CI) return;
    int ci = i / (CO * 9);
    int r  = i % (CO * 9);
    int co = r / 9;
    int tp = r % 9;
    wp[((size_t)tp * CO + co) * CI + ci] = f2bf(w[i]);
}

// ---------------------------------------------------------------------------
// MFMA ConvTranspose2d k=3 s=2 p=1 op=1 + ReLU, bf16.
// Input NHWC bf16. Block 256 = 4 waves: 64 co x (16x by 4y input patch).
// Per parity class (ry,rx): taps per round-1 verified decomposition.
// Wave tile: 16co x 16x at y=s; acc[s][class] = 4 x f32 (D: col=lane&15=x,
// row=quad*4+r=co).  A-frags direct from L2 (packed [tap][co][ci]).
// ---------------------------------------------------------------------------
template<int CIN, int COUT, int IH, int IW, bool OUT_NCHW>
__global__ __launch_bounds__(256)
void deconv_mfma_kernel(const unsigned short* __restrict__ in,   // NHWC bf16
                        const unsigned short* __restrict__ wp,   // [9][CO][CI] bf16
                        const float* __restrict__ bias,
                        unsigned short* __restrict__ out)        // bf16
{
    constexpr int OH = 2 * IH, OW = 2 * IW;
    __shared__ short sIn[5][17][40];   // [y][x][ci-chunk padded 32->40]

    const int tid = threadIdx.x;
    const int lane = tid & 63;
    const int wave = tid >> 6;
    const int n16 = lane & 15;
    const int quad = lane >> 4;

    constexpr int NTX = IW / 16;
    const int x0 = (blockIdx.x % NTX) * 16;
    const int y0 = (blockIdx.x / NTX) * 4;
    const int co0 = blockIdx.y * 64 + wave * 16;
    const int img = blockIdx.z;

    const unsigned short* inN = in + (size_t)img * IH * IW * CIN;

    floatx4 acc[4][4];  // [s][class ry*2+rx]
#pragma unroll
    for (int s = 0; s < 4; s++)
#pragma unroll
        for (int c = 0; c < 4; c++) acc[s][c] = (floatx4){0.f, 0.f, 0.f, 0.f};

    for (int k0 = 0; k0 < CIN; k0 += 32) {
        __syncthreads();
        // stage [5][17][32] input chunk (zero beyond boundary)
        for (int e = tid; e < 340; e += 256) {
            int yy = e / 68, r = e % 68;
            int xx = r >> 2, q4 = r & 3;
            int gy = y0 + yy, gx = x0 + xx;
            short8 v = {0, 0, 0, 0, 0, 0, 0, 0};
            if (gy < IH && gx < IW)
                v = *(const short8*)(inN + ((size_t)(gy * IW + gx) * CIN + k0 + q4 * 8));
            *(short8*)&sIn[yy][xx][q4 * 8] = v;
        }
        __syncthreads();

        short8 a[9];
#pragma unroll
        for (int tp = 0; tp < 9; tp++)
            a[tp] = *(const short8*)(wp + ((size_t)(tp * COUT + co0 + n16) * CIN + k0 + quad * 8));

#pragma unroll
        for (int s = 0; s < 4; s++) {
            short8 b00 = *(const short8*)&sIn[s    ][n16    ][quad * 8];
            short8 b01 = *(const short8*)&sIn[s    ][n16 + 1][quad * 8];
            short8 b10 = *(const short8*)&sIn[s + 1][n16    ][quad * 8];
            short8 b11 = *(const short8*)&sIn[s + 1][n16 + 1][quad * 8];
            acc[s][0] = __builtin_amdgcn_mfma_f32_16x16x32_bf16(a[4], b00, acc[s][0], 0, 0, 0);
            acc[s][1] = __builtin_amdgcn_mfma_f32_16x16x32_bf16(a[3], b01, acc[s][1], 0, 0, 0);
            acc[s][1] = __builtin_amdgcn_mfma_f32_16x16x32_bf16(a[5], b00, acc[s][1], 0, 0, 0);
            acc[s][2] = __builtin_amdgcn_mfma_f32_16x16x32_bf16(a[1], b10, acc[s][2], 0, 0, 0);
            acc[s][2] = __builtin_amdgcn_mfma_f32_16x16x32_bf16(a[7], b00, acc[s][2], 0, 0, 0);
            acc[s][3] = __builtin_amdgcn_mfma_f32_16x16x32_bf16(a[0], b11, acc[s][3], 0, 0, 0);
            acc[s][3] = __builtin_amdgcn_mfma_f32_16x16x32_bf16(a[2], b10, acc[s][3], 0, 0, 0);
            acc[s][3] = __builtin_amdgcn_mfma_f32_16x16x32_bf16(a[6], b01, acc[s][3], 0, 0, 0);
            acc[s][3] = __builtin_amdgcn_mfma_f32_16x16x32_bf16(a[8], b00, acc[s][3], 0, 0, 0);
        }
    }

    const float4 bv = *(const float4*)&bias[co0 + quad * 4];
    const float bb[4] = {bv.x, bv.y, bv.z, bv.w};
    const int x = x0 + n16;

    if (!OUT_NCHW) {
        unsigned short* outN = out + (size_t)img * OH * OW * COUT;
#pragma unroll
        for (int s = 0; s < 4; s++) {
            const int y = y0 + s;
#pragma unroll
            for (int c = 0; c < 4; c++) {
                const int oy = 2 * y + (c >> 1);
                const int ox = 2 * x + (c & 1);
                ushort4 h;
                h.x = f2bf(fmaxf(acc[s][c][0] + bb[0], 0.f));
                h.y = f2bf(fmaxf(acc[s][c][1] + bb[1], 0.f));
                h.z = f2bf(fmaxf(acc[s][c][2] + bb[2], 0.f));
                h.w = f2bf(fmaxf(acc[s][c][3] + bb[3], 0.f));
                *(ushort4*)(outN + ((size_t)(oy * OW + ox) * COUT + co0 + quad * 4)) = h;
            }
        }
    } else {
#pragma unroll
        for (int s = 0; s < 4; s++) {
            const int y = y0 + s;
#pragma unroll
            for (int r = 0; r < 4; r++) {
                const int co = co0 + quad * 4 + r;
                unsigned short* oC = out + (size_t)(img * COUT + co) * OH * OW;
                unsigned p0 = (unsigned)f2bf(fmaxf(acc[s][0][r] + bb[r], 0.f)) |
                              ((unsigned)f2bf(fmaxf(acc[s][1][r] + bb[r], 0.f)) << 16);
                unsigned p1 = (unsigned)f2bf(fmaxf(acc[s][2][r] + bb[r], 0.f)) |
                              ((unsigned)f2bf(fmaxf(acc[s][3][r] + bb[r], 0.f)) << 16);
                *(unsigned*)(oC + (size_t)(2 * y) * OW + 2 * x) = p0;
                *(unsigned*)(oC + (size_t)(2 * y + 1) * OW + 2 * x) = p1;
            }
        }
    }
}

// ---------------------------------------------------------------------------
// Final conv 64->3 + sigmoid. NCHW bf16 input, fp32 out (d_out).
// ---------------------------------------------------------------------------
__global__ __launch_bounds__(256)
void conv_out_kernel(const unsigned short* __restrict__ in, // [16,64,256,256] bf16
                     const float* __restrict__ w,           // [3,64,3,3]
                     const float* __restrict__ bias,
                     float* __restrict__ out)               // [16,3,256,256]
{
    constexpr int TIC = 4;
    __shared__ float s_in[TIC][3][258];
    const int t = threadIdx.x;
    const int y = blockIdx.x;
    const int n = blockIdx.y;
    const unsigned short* inN = in + (size_t)n * 64 * 65536;
    float acc0 = bias[0], acc1 = bias[1], acc2 = bias[2];

    for (int c0 = 0; c0 < 64; c0 += TIC) {
        for (int e = t; e < TIC * 3 * 258; e += 256) {
            int ci = e / 774;
            int r  = e % 774;
            int ry = r / 258, xx = r % 258;
            int gy = y - 1 + ry, gx = xx - 1;
            float v = 0.f;
            if ((unsigned)gy < 256u && (unsigned)gx < 256u)
                v = bf2f(inN[(size_t)(c0 + ci) * 65536 + gy * 256 + gx]);
            s_in[ci][ry][xx] = v;
        }
        __syncthreads();
#pragma unroll
        for (int ci = 0; ci < TIC; ++ci) {
            float iv[3][3];
#pragma unroll
            for (int ry = 0; ry < 3; ry++)
#pragma unroll
                for (int kx = 0; kx < 3; kx++)
                    iv[ry][kx] = s_in[ci][ry][t + kx];
#pragma unroll
            for (int k = 0; k < 9; k++) {
                const float v = iv[k / 3][k % 3];
                acc0 += w[(0 * 64 + c0 + ci) * 9 + k] * v;
                acc1 += w[(1 * 64 + c0 + ci) * 9 + k] * v;
                acc2 += w[(2 * 64 + c0 + ci) * 9 + k] * v;
            }
        }
        __syncthreads();
    }
    const size_t o = (size_t)((n * 3 + 0) * 256 + y) * 256 + t;
    out[o]          = 1.f / (1.f + __expf(-acc0));
    out[o + 65536]  = 1.f / (1.f + __expf(-acc1));
    out[o + 131072] = 1.f / (1.f + __expf(-acc2));
}

// ---------------------------------------------------------------------------
// Workspace (peak 201,490,432 B — same as round 3):
//  R0 @0 (134.2M): H2 f32  ->  Z f32 @0 | ZQ bf16 NHWC @33.5M | G1 bf16 @50.3M
//                  | WP1 @83.9M | WP2 @86.2M  ->  G3 bf16 NCHW @0 (full)
//  R1 @134.2M (67.1M): H3 f32 -> G2 bf16 NHWC (full)
//  keys @201.3M (128K) + cn (32K)  ->  WP3 reuses keys/cn region after VQ
// ---------------------------------------------------------------------------
extern "C" void kernel_launch(void* const* d_in, const int* in_sizes, int n_in,
                              void* d_out, int out_size, void* d_ws, size_t ws_size,
                              hipStream_t stream)
{
    const float* x   = (const float*)d_in[0];
    const float* w1  = (const float*)d_in[1];
    const float* b1  = (const float*)d_in[2];
    const float* w2  = (const float*)d_in[3];
    const float* b2  = (const float*)d_in[4];
    const float* w3  = (const float*)d_in[5];
    const float* b3  = (const float*)d_in[6];
    const float* w4  = (const float*)d_in[7];
    const float* b4  = (const float*)d_in[8];
    const float* cb  = (const float*)d_in[9];
    const float* d1w = (const float*)d_in[10];
    const float* d1b = (const float*)d_in[11];
    const float* d2w = (const float*)d_in[12];
    const float* d2b = (const float*)d_in[13];
    const float* d3w = (const float*)d_in[14];
    const float* d3b = (const float*)d_in[15];
    const float* wo  = (const float*)d_in[16];
    const float* bo  = (const float*)d_in[17];

    char* ws = (char*)d_ws;
    float* H2 = (float*)(ws);
    float* H3 = (float*)(ws + 134217728);
    float* Z  = (float*)(ws);
    unsigned short* ZQ  = (unsigned short*)(ws + 33554432);
    unsigned short* G1  = (unsigned short*)(ws + 50331648);
    unsigned short* G2  = (unsigned short*)(ws + 134217728);
    unsigned short* G3  = (unsigned short*)(ws);
    unsigned short* WP1 = (unsigned short*)(ws + 83886080);
    unsigned short* WP2 = (unsigned short*)(ws + 86245376);
    unsigned short* WP3 = (unsigned short*)(ws + 201326592); // over dead keys/cn
    unsigned long long* keys = (unsigned long long*)(ws + 201326592);
    float* cn = (float*)(ws + 201457664);

    float* xrec = (float*)d_out;
    float* idxf = (float*)d_out + (size_t)16 * 3 * 256 * 256;

    // ---- encoder (fp32 — VQ argmin fidelity) ----
    fused_conv12_kernel<<<dim3(128, 2, 16), 256, 0, stream>>>(x, w1, b1, w2, b2, H2);
    conv3x3s2_kernel<4, true ><<<dim3(32, 4, 16), 256, 0, stream>>>(H2, w3, b3, H3, 128, 256, 128, 128, 64, 64);
    conv3x3s2_kernel<4, false><<<dim3(8,  8, 16), 256, 0, stream>>>(H3, w4, b4, Z,  256, 512, 64,  64,  32, 32);

    // ---- vector quantization (fp32 exact) ----
    cnorm_kernel<<<8192, 64, 0, stream>>>(cb, cn);
    init_keys_kernel<<<64, 256, 0, stream>>>(keys);
    vq_dist_kernel<<<dim3(128, 64), 256, 0, stream>>>(Z, cb, cn, keys);
    vq_gather_kernel<<<256, 256, 0, stream>>>(keys, cb, ZQ, idxf);

    // ---- decoder weight prepack (bf16 [tap][co][ci]) ----
    prepack_kernel<512, 256><<<4608, 256, 0, stream>>>(d1w, WP1);
    prepack_kernel<256, 128><<<1152, 256, 0, stream>>>(d2w, WP2);
    prepack_kernel<128, 64 ><<<288,  256, 0, stream>>>(d3w, WP3);

    // ---- decoder (bf16 MFMA) ----
    deconv_mfma_kernel<512, 256, 32,  32,  false><<<dim3(16,  4, 16), 256, 0, stream>>>(ZQ, WP1, d1b, G1);
    deconv_mfma_kernel<256, 128, 64,  64,  false><<<dim3(64,  2, 16), 256, 0, stream>>>(G1, WP2, d2b, G2);
    deconv_mfma_kernel<128, 64,  128, 128, true ><<<dim3(256, 1, 16), 256, 0, stream>>>(G2, WP3, d3b, G3);
    conv_out_kernel<<<dim3(256, 16), 256, 0, stream>>>(G3, wo, bo, xrec);
}

// Round 5
// 5383.194 us; speedup vs baseline: 4.7642x; 4.7642x over previous
//
#include <hip/hip_runtime.h>
#include <cstddef>

typedef short short8 __attribute__((ext_vector_type(8)));
typedef _Float16 half8 __attribute__((ext_vector_type(8)));
typedef float floatx4 __attribute__((ext_vector_type(4)));

// ---- bf16 helpers (round-to-nearest-even) ---------------------------------
__device__ __forceinline__ unsigned short f2bf(float f) {
    unsigned u = __float_as_uint(f);
    u += 0x7FFFu + ((u >> 16) & 1u);
    return (unsigned short)(u >> 16);
}
__device__ __forceinline__ float bf2f(unsigned short h) {
    return __uint_as_float((unsigned)h << 16);
}

// ---------------------------------------------------------------------------
// Fused conv1(3->64,s1) + relu + conv2(64->128,s2) + relu.  fp32 (VQ fidelity)
// ---------------------------------------------------------------------------
__global__ __launch_bounds__(256)
void fused_conv12_kernel(const float* __restrict__ x,   // [16,3,256,256]
                         const float* __restrict__ w1,  // [64,3,3,3]
                         const float* __restrict__ b1,
                         const float* __restrict__ w2,  // [128,64,3,3]
                         const float* __restrict__ b2,
                         float* __restrict__ out)       // [16,128,128,128]
{
    __shared__ float s_x[3][11][67];
    __shared__ float s_w1[64][28];
    __shared__ float s_h1[8][9][65];
    __shared__ float s_w2[72][65];

    const int tid = threadIdx.x;
    const int tx = tid & 15, ty = tid >> 4;
    const int tileX = blockIdx.x & 3;
    const int tileY = blockIdx.x >> 2;
    const int x0 = tileX * 32, y0 = tileY * 4;
    const int co0 = blockIdx.y * 64;
    const int n = blockIdx.z;
    const float* xN = x + (size_t)n * 3 * 65536;

    const int gy0 = 2 * y0 - 2, gx0 = 2 * x0 - 2;
    const int hy0 = 2 * y0 - 1, hx0 = 2 * x0 - 1;

    for (int e = tid; e < 3 * 11 * 67; e += 256) {
        int c = e / 737, r = e % 737;
        int yy = r / 67, xx = r % 67;
        int gy = gy0 + yy, gx = gx0 + xx;
        float v = 0.f;
        if ((unsigned)gy < 256u && (unsigned)gx < 256u)
            v = xN[(size_t)c * 65536 + gy * 256 + gx];
        s_x[c][yy][xx] = v;
    }
    for (int e = tid; e < 64 * 27; e += 256)
        s_w1[e / 27][e % 27] = w1[e];

    float acc[4][4][2] = {};

    for (int ci0 = 0; ci0 < 64; ci0 += 8) {
        __syncthreads();
        for (int e = tid; e < 8 * 9 * 65; e += 256) {
            int m = e / 585, r = e % 585;
            int ly = r / 65, lx = r % 65;
            float v = 0.f;
            if ((unsigned)(hy0 + ly) < 256u && (unsigned)(hx0 + lx) < 256u) {
                const int gm = ci0 + m;
                float s = b1[gm];
#pragma unroll
                for (int c = 0; c < 3; c++)
#pragma unroll
                    for (int ky = 0; ky < 3; ky++)
#pragma unroll
                        for (int kx = 0; kx < 3; kx++)
                            s += s_w1[gm][c * 9 + ky * 3 + kx] * s_x[c][ly + ky][lx + kx];
                v = fmaxf(s, 0.f);
            }
            s_h1[m][ly][lx] = v;
        }
        for (int e = tid; e < 64 * 72; e += 256) {
            int co = e / 72, r = e % 72;
            s_w2[r][co] = w2[(size_t)(co0 + co) * 576 + ci0 * 9 + r];
        }
        __syncthreads();
#pragma unroll
        for (int ci = 0; ci < 8; ++ci) {
#pragma unroll
            for (int k = 0; k < 9; ++k) {
                const int ky = k / 3, kx = k % 3;
                float wv[4];
#pragma unroll
                for (int i = 0; i < 4; i++) wv[i] = s_w2[ci * 9 + k][ty * 4 + i];
                float iv[4][2];
#pragma unroll
                for (int j = 0; j < 4; j++) {
                    iv[j][0] = s_h1[ci][j * 2 + ky][(tx * 2 + 0) * 2 + kx];
                    iv[j][1] = s_h1[ci][j * 2 + ky][(tx * 2 + 1) * 2 + kx];
                }
#pragma unroll
                for (int i = 0; i < 4; i++)
#pragma unroll
                    for (int j = 0; j < 4; j++) {
                        acc[i][j][0] += wv[i] * iv[j][0];
                        acc[i][j][1] += wv[i] * iv[j][1];
                    }
            }
        }
    }
#pragma unroll
    for (int i = 0; i < 4; i++) {
        const int co = co0 + ty * 4 + i;
        const float b = b2[co];
#pragma unroll
        for (int j = 0; j < 4; j++) {
            float2 v;
            v.x = fmaxf(acc[i][j][0] + b, 0.f);
            v.y = fmaxf(acc[i][j][1] + b, 0.f);
            *(float2*)(out + (size_t)((n * 128 + co) * 128 + (y0 + j)) * 128 + x0 + tx * 2) = v;
        }
    }
}

// ---------------------------------------------------------------------------
// 3x3 conv s=2 fp32 (encoder conv3/conv4)
// ---------------------------------------------------------------------------
template<int TIC, bool RELU>
__global__ __launch_bounds__(256)
void conv3x3s2_kernel(const float* __restrict__ in, const float* __restrict__ w,
                      const float* __restrict__ bias, float* __restrict__ out,
                      int CIN, int COUT, int IH, int IW, int OH, int OW)
{
    constexpr int IYT = 9, IXT = 65;
    __shared__ float s_in[TIC][IYT][IXT];
    __shared__ float s_w[TIC * 9][65];

    const int tid = threadIdx.x;
    const int tx = tid & 15;
    const int ty = tid >> 4;

    const int ntx = OW / 32;
    const int tileX = blockIdx.x % ntx;
    const int tileY = blockIdx.x / ntx;
    const int x0 = tileX * 32;
    const int y0 = tileY * 4;
    const int co0 = blockIdx.y * 64;
    const int n = blockIdx.z;

    const float* inN = in + (size_t)n * CIN * IH * IW;

    float acc[4][4][2] = {};

    const int iy0 = y0 * 2 - 1;
    const int ix0 = x0 * 2 - 1;

    for (int c0 = 0; c0 < CIN; c0 += TIC) {
        for (int e = tid; e < TIC * IYT * IXT; e += 256) {
            int ci = e / (IYT * IXT);
            int r  = e % (IYT * IXT);
            int yy = r / IXT, xx = r % IXT;
            int gy = iy0 + yy, gx = ix0 + xx;
            float v = 0.f;
            if ((unsigned)gy < (unsigned)IH && (unsigned)gx < (unsigned)IW)
                v = inN[(size_t)(c0 + ci) * IH * IW + (size_t)gy * IW + gx];
            s_in[ci][yy][xx] = v;
        }
        for (int e = tid; e < 64 * TIC * 9; e += 256) {
            int co = e / (TIC * 9);
            int r  = e % (TIC * 9);
            s_w[r][co] = w[(size_t)(co0 + co) * CIN * 9 + (size_t)c0 * 9 + r];
        }
        __syncthreads();
#pragma unroll
        for (int ci = 0; ci < TIC; ++ci) {
#pragma unroll
            for (int k = 0; k < 9; ++k) {
                const int ky = k / 3, kx = k % 3;
                float wv[4];
#pragma unroll
                for (int i = 0; i < 4; i++) wv[i] = s_w[ci * 9 + k][ty * 4 + i];
                float iv[4][2];
#pragma unroll
                for (int j = 0; j < 4; j++) {
                    iv[j][0] = s_in[ci][j * 2 + ky][(tx * 2 + 0) * 2 + kx];
                    iv[j][1] = s_in[ci][j * 2 + ky][(tx * 2 + 1) * 2 + kx];
                }
#pragma unroll
                for (int i = 0; i < 4; i++)
#pragma unroll
                    for (int j = 0; j < 4; j++) {
                        acc[i][j][0] += wv[i] * iv[j][0];
                        acc[i][j][1] += wv[i] * iv[j][1];
                    }
            }
        }
        __syncthreads();
    }

#pragma unroll
    for (int i = 0; i < 4; i++) {
        const int co = co0 + ty * 4 + i;
        const float b = bias[co];
#pragma unroll
        for (int j = 0; j < 4; j++) {
            float2 v;
            v.x = acc[i][j][0] + b;
            v.y = acc[i][j][1] + b;
            if (RELU) { v.x = fmaxf(v.x, 0.f); v.y = fmaxf(v.y, 0.f); }
            *(float2*)(out + (size_t)((n * COUT + co) * OH + (y0 + j)) * OW + x0 + tx * 2) = v;
        }
    }
}

// ---------------------------------------------------------------------------
__global__ __launch_bounds__(64)
void cnorm_kernel(const float* __restrict__ cb, float* __restrict__ cn)
{
    const int code = blockIdx.x;
    const int t = threadIdx.x;
    const float* row = cb + (size_t)code * 512;
    float s = 0.f;
    for (int i = t; i < 512; i += 64) s += row[i] * row[i];
#pragma unroll
    for (int off = 32; off > 0; off >>= 1) s += __shfl_down(s, off, 64);
    if (t == 0) cn[code] = s;
}

__global__ __launch_bounds__(256)
void init_keys_kernel(unsigned long long* __restrict__ keys)
{
    keys[blockIdx.x * 256 + threadIdx.x] = ~0ull;
}

// ---------------------------------------------------------------------------
// Split codebook into fp16 hi + scaled residual lo (x1024, keeps fp16 normal).
// ---------------------------------------------------------------------------
__global__ __launch_bounds__(256)
void split_cb_kernel(const float* __restrict__ cb,
                     _Float16* __restrict__ ch, _Float16* __restrict__ cl)
{
    size_t i = (size_t)blockIdx.x * 256 + threadIdx.x;   // 8192*512 elems
    float v = cb[i];
    _Float16 h = (_Float16)v;
    ch[i] = h;
    cl[i] = (_Float16)((v - (float)h) * 1024.f);
}

// ---------------------------------------------------------------------------
// Split + transpose z: NCHW fp32 [16,512,32,32] -> row-major [16384][512]
// fp16 hi + scaled residual. LDS-transposed for coalescing both sides.
// ---------------------------------------------------------------------------
__global__ __launch_bounds__(256)
void split_z_kernel(const float* __restrict__ z,
                    _Float16* __restrict__ zh, _Float16* __restrict__ zl)
{
    __shared__ float s[64][65];
    const int tid = threadIdx.x;
    const int n = blockIdx.x >> 4;
    const int hw0 = (blockIdx.x & 15) * 64;
    const float* zN = z + (size_t)n * 512 * 1024;

    for (int k0 = 0; k0 < 512; k0 += 64) {
        __syncthreads();
        for (int e = tid; e < 4096; e += 256) {
            int kk = e >> 6, hh = e & 63;
            s[kk][hh] = zN[(size_t)(k0 + kk) * 1024 + hw0 + hh];
        }
        __syncthreads();
        for (int e = tid; e < 4096; e += 256) {
            int rr = e >> 6, kk = e & 63;
            float v = s[kk][rr];
            _Float16 h = (_Float16)v;
            size_t o = (size_t)(n * 1024 + hw0 + rr) * 512 + k0 + kk;
            zh[o] = h;
            zl[o] = (_Float16)((v - (float)h) * 1024.f);
        }
    }
}

// ---------------------------------------------------------------------------
// VQ distance GEMM via fp16 split-precision MFMA + argmin.
// z.c = zh.ch + (zh.cl + zl.ch)/1024  (~22-bit mantissa; lo.lo ~2^-22 dropped)
// Block 256 = 4 waves; block tile 128 rows x 64 codes; wave = 32 rows x 64.
// A/B frags read DIRECT from global (row-major [*][512] fp16, 16B loads).
// D layout: col(lane&15)=code, row(quad*4+reg)=z-row.
// ---------------------------------------------------------------------------
__global__ __launch_bounds__(256)
void vq_mfma_kernel(const _Float16* __restrict__ zh, const _Float16* __restrict__ zl,
                    const _Float16* __restrict__ ch, const _Float16* __restrict__ cl,
                    const float* __restrict__ cn,
                    unsigned long long* __restrict__ keys)   // [16384]
{
    const int tid = threadIdx.x;
    const int lane = tid & 63;
    const int wave = tid >> 6;
    const int n16 = lane & 15;
    const int quad = lane >> 4;

    const int row0 = blockIdx.x * 128 + wave * 32;
    const int code0 = blockIdx.y * 64;

    floatx4 acc1[2][4], acc2[2][4];
#pragma unroll
    for (int rt = 0; rt < 2; rt++)
#pragma unroll
        for (int ct = 0; ct < 4; ct++) {
            acc1[rt][ct] = (floatx4){0.f, 0.f, 0.f, 0.f};
            acc2[rt][ct] = (floatx4){0.f, 0.f, 0.f, 0.f};
        }

    const _Float16* zh0 = zh + (size_t)(row0 + n16) * 512 + quad * 8;
    const _Float16* zh1 = zh0 + 16 * 512;
    const _Float16* zl0 = zl + (size_t)(row0 + n16) * 512 + quad * 8;
    const _Float16* zl1 = zl0 + 16 * 512;
    const _Float16* chp = ch + (size_t)(code0 + n16) * 512 + quad * 8;
    const _Float16* clp = cl + (size_t)(code0 + n16) * 512 + quad * 8;

#pragma unroll 2
    for (int k0 = 0; k0 < 512; k0 += 32) {
        half8 ah0 = *(const half8*)(zh0 + k0);
        half8 ah1 = *(const half8*)(zh1 + k0);
        half8 al0 = *(const half8*)(zl0 + k0);
        half8 al1 = *(const half8*)(zl1 + k0);
#pragma unroll
        for (int ct = 0; ct < 4; ct++) {
            half8 bh = *(const half8*)(chp + (size_t)ct * 16 * 512 + k0);
            half8 bl = *(const half8*)(clp + (size_t)ct * 16 * 512 + k0);
            acc1[0][ct] = __builtin_amdgcn_mfma_f32_16x16x32_f16(ah0, bh, acc1[0][ct], 0, 0, 0);
            acc1[1][ct] = __builtin_amdgcn_mfma_f32_16x16x32_f16(ah1, bh, acc1[1][ct], 0, 0, 0);
            acc2[0][ct] = __builtin_amdgcn_mfma_f32_16x16x32_f16(ah0, bl, acc2[0][ct], 0, 0, 0);
            acc2[1][ct] = __builtin_amdgcn_mfma_f32_16x16x32_f16(ah1, bl, acc2[1][ct], 0, 0, 0);
            acc2[0][ct] = __builtin_amdgcn_mfma_f32_16x16x32_f16(al0, bh, acc2[0][ct], 0, 0, 0);
            acc2[1][ct] = __builtin_amdgcn_mfma_f32_16x16x32_f16(al1, bh, acc2[1][ct], 0, 0, 0);
        }
    }

    // per-row argmin: in-lane over ct, cross-lane over n16 (codes), atomic.
#pragma unroll
    for (int rt = 0; rt < 2; rt++) {
#pragma unroll
        for (int reg = 0; reg < 4; reg++) {
            float best = 3.0e38f;
            int bcode = 0;
#pragma unroll
            for (int ct = 0; ct < 4; ct++) {
                const int code = code0 + ct * 16 + n16;
                float dot = acc1[rt][ct][reg] + acc2[rt][ct][reg] * (1.0f / 1024.0f);
                float s = cn[code] - 2.0f * dot;
                if (s < best) { best = s; bcode = code; }
            }
            unsigned u = __float_as_uint(best);
            u = (u & 0x80000000u) ? ~u : (u | 0x80000000u);
            unsigned long long key = ((unsigned long long)u << 32) | (unsigned)bcode;
#pragma unroll
            for (int m = 1; m < 16; m <<= 1) {
                unsigned long long o = __shfl_xor(key, m, 64);
                key = (o < key) ? o : key;
            }
            if (n16 == 0)
                atomicMin(&keys[row0 + rt * 16 + quad * 4 + reg], key);
        }
    }
}

// ---------------------------------------------------------------------------
// Gather: indices (float) into d_out tail, zq as bf16 NHWC [16,32,32,512].
// ---------------------------------------------------------------------------
__global__ __launch_bounds__(256)
void vq_gather_kernel(const unsigned long long* __restrict__ keys,
                      const float* __restrict__ cb,
                      unsigned short* __restrict__ zq, float* __restrict__ idx_out)
{
    __shared__ int sidx[64];
    const int t = threadIdx.x;
    const int v0 = blockIdx.x * 64;
    if (t < 64) {
        int idx = (int)(keys[v0 + t] & 0xFFFFFFFFull);
        sidx[t] = idx;
        idx_out[v0 + t] = (float)idx;
    }
    __syncthreads();
    const int tv = t >> 2;
    const int q = t & 3;
    const float* crow = cb + (size_t)sidx[tv] * 512;
    unsigned short* zrow = zq + (size_t)(v0 + tv) * 512;
    for (int c = q * 8; c < 512; c += 32) {
        float4 f0 = *(const float4*)(crow + c);
        float4 f1 = *(const float4*)(crow + c + 4);
        short8 h;
        h[0] = (short)f2bf(f0.x); h[1] = (short)f2bf(f0.y);
        h[2] = (short)f2bf(f0.z); h[3] = (short)f2bf(f0.w);
        h[4] = (short)f2bf(f1.x); h[5] = (short)f2bf(f1.y);
        h[6] = (short)f2bf(f1.z); h[7] = (short)f2bf(f1.w);
        *(short8*)(zrow + c) = h;
    }
}

// ---------------------------------------------------------------------------
// Weight prepack: torch [CI][CO][3][3] f32 -> [tap][CO][CI] bf16
// ---------------------------------------------------------------------------
template<int CI, int CO>
__global__ __launch_bounds__(256)
void prepack_kernel(const float* __restrict__ w, unsigned short* __restrict__ wp)
{
    int i = blockIdx.x * 256 + threadIdx.x;
    if (i >= 9 * CO * CI) return;
    int ci = i / (CO * 9);
    int r  = i % (CO * 9);
    int co = r / 9;
    int tp = r % 9;
    wp[((size_t)tp * CO + co) * CI + ci] = f2bf(w[i]);
}

// ---------------------------------------------------------------------------
// MFMA ConvTranspose2d k=3 s=2 p=1 op=1 + ReLU, bf16.
// ---------------------------------------------------------------------------
template<int CIN, int COUT, int IH, int IW, bool OUT_NCHW>
__global__ __launch_bounds__(256)
void deconv_mfma_kernel(const unsigned short* __restrict__ in,   // NHWC bf16
                        const unsigned short* __restrict__ wp,   // [9][CO][CI] bf16
                        const float* __restrict__ bias,
                        unsigned short* __restrict__ out)        // bf16
{
    constexpr int OH = 2 * IH, OW = 2 * IW;
    __shared__ short sIn[5][17][40];

    const int tid = threadIdx.x;
    const int lane = tid & 63;
    const int wave = tid >> 6;
    const int n16 = lane & 15;
    const int quad = lane >> 4;

    constexpr int NTX = IW / 16;
    const int x0 = (blockIdx.x % NTX) * 16;
    const int y0 = (blockIdx.x / NTX) * 4;
    const int co0 = blockIdx.y * 64 + wave * 16;
    const int img = blockIdx.z;

    const unsigned short* inN = in + (size_t)img * IH * IW * CIN;

    floatx4 acc[4][4];
#pragma unroll
    for (int s = 0; s < 4; s++)
#pragma unroll
        for (int c = 0; c < 4; c++) acc[s][c] = (floatx4){0.f, 0.f, 0.f, 0.f};

    for (int k0 = 0; k0 < CIN; k0 += 32) {
        __syncthreads();
        for (int e = tid; e < 340; e += 256) {
            int yy = e / 68, r = e % 68;
            int xx = r >> 2, q4 = r & 3;
            int gy = y0 + yy, gx = x0 + xx;
            short8 v = {0, 0, 0, 0, 0, 0, 0, 0};
            if (gy < IH && gx < IW)
                v = *(const short8*)(inN + ((size_t)(gy * IW + gx) * CIN + k0 + q4 * 8));
            *(short8*)&sIn[yy][xx][q4 * 8] = v;
        }
        __syncthreads();

        short8 a[9];
#pragma unroll
        for (int tp = 0; tp < 9; tp++)
            a[tp] = *(const short8*)(wp + ((size_t)(tp * COUT + co0 + n16) * CIN + k0 + quad * 8));

#pragma unroll
        for (int s = 0; s < 4; s++) {
            short8 b00 = *(const short8*)&sIn[s    ][n16    ][quad * 8];
            short8 b01 = *(const short8*)&sIn[s    ][n16 + 1][quad * 8];
            short8 b10 = *(const short8*)&sIn[s + 1][n16    ][quad * 8];
            short8 b11 = *(const short8*)&sIn[s + 1][n16 + 1][quad * 8];
            acc[s][0] = __builtin_amdgcn_mfma_f32_16x16x32_bf16(a[4], b00, acc[s][0], 0, 0, 0);
            acc[s][1] = __builtin_amdgcn_mfma_f32_16x16x32_bf16(a[3], b01, acc[s][1], 0, 0, 0);
            acc[s][1] = __builtin_amdgcn_mfma_f32_16x16x32_bf16(a[5], b00, acc[s][1], 0, 0, 0);
            acc[s][2] = __builtin_amdgcn_mfma_f32_16x16x32_bf16(a[1], b10, acc[s][2], 0, 0, 0);
            acc[s][2] = __builtin_amdgcn_mfma_f32_16x16x32_bf16(a[7], b00, acc[s][2], 0, 0, 0);
            acc[s][3] = __builtin_amdgcn_mfma_f32_16x16x32_bf16(a[0], b11, acc[s][3], 0, 0, 0);
            acc[s][3] = __builtin_amdgcn_mfma_f32_16x16x32_bf16(a[2], b10, acc[s][3], 0, 0, 0);
            acc[s][3] = __builtin_amdgcn_mfma_f32_16x16x32_bf16(a[6], b01, acc[s][3], 0, 0, 0);
            acc[s][3] = __builtin_amdgcn_mfma_f32_16x16x32_bf16(a[8], b00, acc[s][3], 0, 0, 0);
        }
    }

    const float4 bv = *(const float4*)&bias[co0 + quad * 4];
    const float bb[4] = {bv.x, bv.y, bv.z, bv.w};
    const int x = x0 + n16;

    if (!OUT_NCHW) {
        unsigned short* outN = out + (size_t)img * OH * OW * COUT;
#pragma unroll
        for (int s = 0; s < 4; s++) {
            const int y = y0 + s;
#pragma unroll
            for (int c = 0; c < 4; c++) {
                const int oy = 2 * y + (c >> 1);
                const int ox = 2 * x + (c & 1);
                ushort4 h;
                h.x = f2bf(fmaxf(acc[s][c][0] + bb[0], 0.f));
                h.y = f2bf(fmaxf(acc[s][c][1] + bb[1], 0.f));
                h.z = f2bf(fmaxf(acc[s][c][2] + bb[2], 0.f));
                h.w = f2bf(fmaxf(acc[s][c][3] + bb[3], 0.f));
                *(ushort4*)(outN + ((size_t)(oy * OW + ox) * COUT + co0 + quad * 4)) = h;
            }
        }
    } else {
#pragma unroll
        for (int s = 0; s < 4; s++) {
            const int y = y0 + s;
#pragma unroll
            for (int r = 0; r < 4; r++) {
                const int co = co0 + quad * 4 + r;
                unsigned short* oC = out + (size_t)(img * COUT + co) * OH * OW;
                unsigned p0 = (unsigned)f2bf(fmaxf(acc[s][0][r] + bb[r], 0.f)) |
                              ((unsigned)f2bf(fmaxf(acc[s][1][r] + bb[r], 0.f)) << 16);
                unsigned p1 = (unsigned)f2bf(fmaxf(acc[s][2][r] + bb[r], 0.f)) |
                              ((unsigned)f2bf(fmaxf(acc[s][3][r] + bb[r], 0.f)) << 16);
                *(unsigned*)(oC + (size_t)(2 * y) * OW + 2 * x) = p0;
                *(unsigned*)(oC + (size_t)(2 * y + 1) * OW + 2 * x) = p1;
            }
        }
    }
}

// ---------------------------------------------------------------------------
// Final conv 64->3 + sigmoid. NCHW bf16 input, fp32 out (d_out).
// ---------------------------------------------------------------------------
__global__ __launch_bounds__(256)
void conv_out_kernel(const unsigned short* __restrict__ in, // [16,64,256,256] bf16
                     const float* __restrict__ w,           // [3,64,3,3]
                     const float* __restrict__ bias,
                     float* __restrict__ out)               // [16,3,256,256]
{
    constexpr int TIC = 4;
    __shared__ float s_in[TIC][3][258];
    const int t = threadIdx.x;
    const int y = blockIdx.x;
    const int n = blockIdx.y;
    const unsigned short* inN = in + (size_t)n * 64 * 65536;
    float acc0 = bias[0], acc1 = bias[1], acc2 = bias[2];

    for (int c0 = 0; c0 < 64; c0 += TIC) {
        for (int e = t; e < TIC * 3 * 258; e += 256) {
            int ci = e / 774;
            int r  = e % 774;
            int ry = r / 258, xx = r % 258;
            int gy = y - 1 + ry, gx = xx - 1;
            float v = 0.f;
            if ((unsigned)gy < 256u && (unsigned)gx < 256u)
                v = bf2f(inN[(size_t)(c0 + ci) * 65536 + gy * 256 + gx]);
            s_in[ci][ry][xx] = v;
        }
        __syncthreads();
#pragma unroll
        for (int ci = 0; ci < TIC; ++ci) {
            float iv[3][3];
#pragma unroll
            for (int ry = 0; ry < 3; ry++)
#pragma unroll
                for (int kx = 0; kx < 3; kx++)
                    iv[ry][kx] = s_in[ci][ry][t + kx];
#pragma unroll
            for (int k = 0; k < 9; k++) {
                const float v = iv[k / 3][k % 3];
                acc0 += w[(0 * 64 + c0 + ci) * 9 + k] * v;
                acc1 += w[(1 * 64 + c0 + ci) * 9 + k] * v;
                acc2 += w[(2 * 64 + c0 + ci) * 9 + k] * v;
            }
        }
        __syncthreads();
    }
    const size_t o = (size_t)((n * 3 + 0) * 256 + y) * 256 + t;
    out[o]          = 1.f / (1.f + __expf(-acc0));
    out[o + 65536]  = 1.f / (1.f + __expf(-acc1));
    out[o + 131072] = 1.f / (1.f + __expf(-acc2));
}

// ---------------------------------------------------------------------------
// Workspace (peak 201.5 MB, same as round 3/4):
//  [0, 33.5M)        Z f32 (over dead H2)
//  [33.5M, 50.3M)    ZQ bf16 NHWC
//  [50.3M, 67.1M)    zh fp16   (dead before G1 is written at 50.3-83.9M)
//  [67.1M, 83.9M)    zl fp16
//  [83.9M, 86.3M)    WP1 ; [86.3M, ...) WP2
//  [134.2M, 142.6M)  cbh fp16  (over dead H3; dead before G2 written here)
//  [142.6M, 151.0M)  cbl fp16
//  [201.3M) keys(128K) + cn(32K);  WP3 over keys after gather
//  G3 bf16 @0 (full 134.2M)
// ---------------------------------------------------------------------------
extern "C" void kernel_launch(void* const* d_in, const int* in_sizes, int n_in,
                              void* d_out, int out_size, void* d_ws, size_t ws_size,
                              hipStream_t stream)
{
    const float* x   = (const float*)d_in[0];
    const float* w1  = (const float*)d_in[1];
    const float* b1  = (const float*)d_in[2];
    const float* w2  = (const float*)d_in[3];
    const float* b2  = (const float*)d_in[4];
    const float* w3  = (const float*)d_in[5];
    const float* b3  = (const float*)d_in[6];
    const float* w4  = (const float*)d_in[7];
    const float* b4  = (const float*)d_in[8];
    const float* cb  = (const float*)d_in[9];
    const float* d1w = (const float*)d_in[10];
    const float* d1b = (const float*)d_in[11];
    const float* d2w = (const float*)d_in[12];
    const float* d2b = (const float*)d_in[13];
    const float* d3w = (const float*)d_in[14];
    const float* d3b = (const float*)d_in[15];
    const float* wo  = (const float*)d_in[16];
    const float* bo  = (const float*)d_in[17];

    char* ws = (char*)d_ws;
    float* H2 = (float*)(ws);
    float* H3 = (float*)(ws + 134217728);
    float* Z  = (float*)(ws);
    unsigned short* ZQ  = (unsigned short*)(ws + 33554432);
    _Float16* ZH = (_Float16*)(ws + 50331648);
    _Float16* ZL = (_Float16*)(ws + 67108864);
    unsigned short* G1  = (unsigned short*)(ws + 50331648);
    unsigned short* G2  = (unsigned short*)(ws + 134217728);
    unsigned short* G3  = (unsigned short*)(ws);
    unsigned short* WP1 = (unsigned short*)(ws + 83886080);
    unsigned short* WP2 = (unsigned short*)(ws + 86245376);
    _Float16* CBH = (_Float16*)(ws + 134217728);
    _Float16* CBL = (_Float16*)(ws + 142606336);
    unsigned short* WP3 = (unsigned short*)(ws + 201326592);
    unsigned long long* keys = (unsigned long long*)(ws + 201326592);
    float* cn = (float*)(ws + 201457664);

    float* xrec = (float*)d_out;
    float* idxf = (float*)d_out + (size_t)16 * 3 * 256 * 256;

    // ---- encoder (fp32 — VQ argmin fidelity) ----
    fused_conv12_kernel<<<dim3(128, 2, 16), 256, 0, stream>>>(x, w1, b1, w2, b2, H2);
    conv3x3s2_kernel<4, true ><<<dim3(32, 4, 16), 256, 0, stream>>>(H2, w3, b3, H3, 128, 256, 128, 128, 64, 64);
    conv3x3s2_kernel<4, false><<<dim3(8,  8, 16), 256, 0, stream>>>(H3, w4, b4, Z,  256, 512, 64,  64,  32, 32);

    // ---- VQ: fp16 split-precision MFMA distance + exact-order argmin ----
    cnorm_kernel<<<8192, 64, 0, stream>>>(cb, cn);
    init_keys_kernel<<<64, 256, 0, stream>>>(keys);
    split_cb_kernel<<<16384, 256, 0, stream>>>(cb, CBH, CBL);
    split_z_kernel<<<256, 256, 0, stream>>>(Z, ZH, ZL);
    vq_mfma_kernel<<<dim3(128, 128), 256, 0, stream>>>(ZH, ZL, CBH, CBL, cn, keys);
    vq_gather_kernel<<<256, 256, 0, stream>>>(keys, cb, ZQ, idxf);

    // ---- decoder weight prepack (bf16 [tap][co][ci]) ----
    prepack_kernel<512, 256><<<4608, 256, 0, stream>>>(d1w, WP1);
    prepack_kernel<256, 128><<<1152, 256, 0, stream>>>(d2w, WP2);
    prepack_kernel<128, 64 ><<<288,  256, 0, stream>>>(d3w, WP3);

    // ---- decoder (bf16 MFMA) ----
    deconv_mfma_kernel<512, 256, 32,  32,  false><<<dim3(16,  4, 16), 256, 0, stream>>>(ZQ, WP1, d1b, G1);
    deconv_mfma_kernel<256, 128, 64,  64,  false><<<dim3(64,  2, 16), 256, 0, stream>>>(G1, WP2, d2b, G2);
    deconv_mfma_kernel<128, 64,  128, 128, true ><<<dim3(256, 1, 16), 256, 0, stream>>>(G2, WP3, d3b, G3);
    conv_out_kernel<<<dim3(256, 16), 256, 0, stream>>>(G3, wo, bo, xrec);
}

// Round 6
// 3128.652 us; speedup vs baseline: 8.1973x; 1.7206x over previous
//
#include <hip/hip_runtime.h>
#include <cstddef>

typedef short short8 __attribute__((ext_vector_type(8)));
typedef _Float16 half8 __attribute__((ext_vector_type(8)));
typedef _Float16 half4 __attribute__((ext_vector_type(4)));
typedef float floatx4 __attribute__((ext_vector_type(4)));

// ---- bf16 helpers (round-to-nearest-even) ---------------------------------
__device__ __forceinline__ unsigned short f2bf(float f) {
    unsigned u = __float_as_uint(f);
    u += 0x7FFFu + ((u >> 16) & 1u);
    return (unsigned short)(u >> 16);
}
__device__ __forceinline__ float bf2f(unsigned short h) {
    return __uint_as_float((unsigned)h << 16);
}

// ---------------------------------------------------------------------------
// Fused conv1(3->64,s1) + relu + conv2(64->128,s2) + relu.  fp32 compute,
// epilogue splits to fp16 hi + residual*1024 lo, NHWC [16][128][128][128].
// ---------------------------------------------------------------------------
__global__ __launch_bounds__(256)
void fused_conv12_kernel(const float* __restrict__ x,   // [16,3,256,256]
                         const float* __restrict__ w1,  // [64,3,3,3]
                         const float* __restrict__ b1,
                         const float* __restrict__ w2,  // [128,64,3,3]
                         const float* __restrict__ b2,
                         _Float16* __restrict__ outH,
                         _Float16* __restrict__ outL)
{
    __shared__ float s_x[3][11][67];
    __shared__ float s_w1[64][28];
    __shared__ float s_h1[8][9][65];
    __shared__ float s_w2[72][65];

    const int tid = threadIdx.x;
    const int tx = tid & 15, ty = tid >> 4;
    const int tileX = blockIdx.x & 3;
    const int tileY = blockIdx.x >> 2;
    const int x0 = tileX * 32, y0 = tileY * 4;
    const int co0 = blockIdx.y * 64;
    const int n = blockIdx.z;
    const float* xN = x + (size_t)n * 3 * 65536;

    const int gy0 = 2 * y0 - 2, gx0 = 2 * x0 - 2;
    const int hy0 = 2 * y0 - 1, hx0 = 2 * x0 - 1;

    for (int e = tid; e < 3 * 11 * 67; e += 256) {
        int c = e / 737, r = e % 737;
        int yy = r / 67, xx = r % 67;
        int gy = gy0 + yy, gx = gx0 + xx;
        float v = 0.f;
        if ((unsigned)gy < 256u && (unsigned)gx < 256u)
            v = xN[(size_t)c * 65536 + gy * 256 + gx];
        s_x[c][yy][xx] = v;
    }
    for (int e = tid; e < 64 * 27; e += 256)
        s_w1[e / 27][e % 27] = w1[e];

    float acc[4][4][2] = {};

    for (int ci0 = 0; ci0 < 64; ci0 += 8) {
        __syncthreads();
        for (int e = tid; e < 8 * 9 * 65; e += 256) {
            int m = e / 585, r = e % 585;
            int ly = r / 65, lx = r % 65;
            float v = 0.f;
            if ((unsigned)(hy0 + ly) < 256u && (unsigned)(hx0 + lx) < 256u) {
                const int gm = ci0 + m;
                float s = b1[gm];
#pragma unroll
                for (int c = 0; c < 3; c++)
#pragma unroll
                    for (int ky = 0; ky < 3; ky++)
#pragma unroll
                        for (int kx = 0; kx < 3; kx++)
                            s += s_w1[gm][c * 9 + ky * 3 + kx] * s_x[c][ly + ky][lx + kx];
                v = fmaxf(s, 0.f);
            }
            s_h1[m][ly][lx] = v;
        }
        for (int e = tid; e < 64 * 72; e += 256) {
            int co = e / 72, r = e % 72;
            s_w2[r][co] = w2[(size_t)(co0 + co) * 576 + ci0 * 9 + r];
        }
        __syncthreads();
#pragma unroll
        for (int ci = 0; ci < 8; ++ci) {
#pragma unroll
            for (int k = 0; k < 9; ++k) {
                const int ky = k / 3, kx = k % 3;
                float wv[4];
#pragma unroll
                for (int i = 0; i < 4; i++) wv[i] = s_w2[ci * 9 + k][ty * 4 + i];
                float iv[4][2];
#pragma unroll
                for (int j = 0; j < 4; j++) {
                    iv[j][0] = s_h1[ci][j * 2 + ky][(tx * 2 + 0) * 2 + kx];
                    iv[j][1] = s_h1[ci][j * 2 + ky][(tx * 2 + 1) * 2 + kx];
                }
#pragma unroll
                for (int i = 0; i < 4; i++)
#pragma unroll
                    for (int j = 0; j < 4; j++) {
                        acc[i][j][0] += wv[i] * iv[j][0];
                        acc[i][j][1] += wv[i] * iv[j][1];
                    }
            }
        }
    }
    float bb[4];
#pragma unroll
    for (int i = 0; i < 4; i++) bb[i] = b2[co0 + ty * 4 + i];
#pragma unroll
    for (int j = 0; j < 4; j++) {
#pragma unroll
        for (int p = 0; p < 2; p++) {
            half4 hv, lv;
#pragma unroll
            for (int i = 0; i < 4; i++) {
                float v = fmaxf(acc[i][j][p] + bb[i], 0.f);
                _Float16 h = (_Float16)v;
                hv[i] = h;
                lv[i] = (_Float16)((v - (float)h) * 1024.f);
            }
            size_t o = ((size_t)(n * 128 + y0 + j) * 128 + (x0 + tx * 2 + p)) * 128
                       + co0 + ty * 4;
            *(half4*)(outH + o) = hv;
            *(half4*)(outL + o) = lv;
        }
    }
}

// ---------------------------------------------------------------------------
// Encoder conv weight prepack: OIHW f32 -> [tap][CO][CI] fp16 hi + lo*1024
// ---------------------------------------------------------------------------
template<int CI, int CO>
__global__ __launch_bounds__(256)
void prepack_conv_kernel(const float* __restrict__ w,
                         _Float16* __restrict__ wh, _Float16* __restrict__ wl)
{
    int i = blockIdx.x * 256 + threadIdx.x;
    if (i >= CO * CI * 9) return;
    int co = i / (CI * 9);
    int r  = i % (CI * 9);
    int ci = r / 9;
    int tp = r % 9;
    float v = w[i];
    _Float16 h = (_Float16)v;
    size_t o = ((size_t)tp * CO + co) * CI + ci;
    wh[o] = h;
    wl[o] = (_Float16)((v - (float)h) * 1024.f);
}

// ---------------------------------------------------------------------------
// Split-precision fp16 MFMA 3x3 conv, stride 2, pad 1.  NHWC hi/lo in & out.
// Block 256 = 4 waves: wave = 16 co; spatial tile 16 ox x 4 oy shared.
// Even/odd-x LDS arrays (pitch 40 halves) -> 2-way conflicts only.
// ---------------------------------------------------------------------------
template<int CIN, int COUT, int IH, int IW, bool RELU>
__global__ __launch_bounds__(256)
void conv_mfma_kernel(const _Float16* __restrict__ inH, const _Float16* __restrict__ inL,
                      const _Float16* __restrict__ wpH, const _Float16* __restrict__ wpL,
                      const float* __restrict__ bias,
                      _Float16* __restrict__ outH, _Float16* __restrict__ outL)
{
    constexpr int OH = IH / 2, OW = IW / 2;
    __shared__ _Float16 sE[2][9][17][40];   // [plane][row][x/2][ci-chunk pad 40]
    __shared__ _Float16 sO[2][9][16][40];

    const int tid = threadIdx.x;
    const int lane = tid & 63;
    const int wave = tid >> 6;
    const int n16 = lane & 15;
    const int quad = lane >> 4;

    constexpr int NTX = OW / 16;
    const int ox0 = (blockIdx.x % NTX) * 16;
    const int oy0 = (blockIdx.x / NTX) * 4;
    const int co0 = blockIdx.y * 64 + wave * 16;
    const int img = blockIdx.z;

    const int iy0 = oy0 * 2 - 1;
    const int ix0 = ox0 * 2 - 1;
    const _Float16* iNH = inH + (size_t)img * IH * IW * CIN;
    const _Float16* iNL = inL + (size_t)img * IH * IW * CIN;

    floatx4 acc1[4], acc2[4];
#pragma unroll
    for (int s = 0; s < 4; s++) {
        acc1[s] = (floatx4){0.f, 0.f, 0.f, 0.f};
        acc2[s] = (floatx4){0.f, 0.f, 0.f, 0.f};
    }

    for (int k0 = 0; k0 < CIN; k0 += 32) {
        __syncthreads();
        // stage 9 x 33 pixels x 32 ci, both planes
        for (int e = tid; e < 2376; e += 256) {
            int pl = e / 1188;
            int r  = e % 1188;
            int pix = r >> 2, q = r & 3;
            int py = pix / 33, px = pix % 33;
            int iy = iy0 + py, ix = ix0 + px;
            half8 v = (half8)(_Float16)0;
            if ((unsigned)iy < (unsigned)IH && (unsigned)ix < (unsigned)IW)
                v = *(const half8*)((pl ? iNL : iNH) + ((size_t)(iy * IW + ix) * CIN + k0 + q * 8));
            if (px & 1) *(half8*)&sO[pl][py][px >> 1][q * 8] = v;
            else        *(half8*)&sE[pl][py][px >> 1][q * 8] = v;
        }
        __syncthreads();

        half8 ah[9], al[9];
#pragma unroll
        for (int tp = 0; tp < 9; tp++) {
            size_t o = ((size_t)(tp * COUT + co0 + n16)) * CIN + k0 + quad * 8;
            ah[tp] = *(const half8*)(wpH + o);
            al[tp] = *(const half8*)(wpL + o);
        }

#pragma unroll
        for (int oy = 0; oy < 4; oy++) {
#pragma unroll
            for (int tp = 0; tp < 9; tp++) {
                const int ky = tp / 3, kx = tp % 3;
                const int row = oy * 2 + ky;
                half8 bh, bl;
                if (kx == 0)      { bh = *(const half8*)&sE[0][row][n16][quad * 8];
                                    bl = *(const half8*)&sE[1][row][n16][quad * 8]; }
                else if (kx == 1) { bh = *(const half8*)&sO[0][row][n16][quad * 8];
                                    bl = *(const half8*)&sO[1][row][n16][quad * 8]; }
                else              { bh = *(const half8*)&sE[0][row][n16 + 1][quad * 8];
                                    bl = *(const half8*)&sE[1][row][n16 + 1][quad * 8]; }
                acc1[oy] = __builtin_amdgcn_mfma_f32_16x16x32_f16(ah[tp], bh, acc1[oy], 0, 0, 0);
                acc2[oy] = __builtin_amdgcn_mfma_f32_16x16x32_f16(ah[tp], bl, acc2[oy], 0, 0, 0);
                acc2[oy] = __builtin_amdgcn_mfma_f32_16x16x32_f16(al[tp], bh, acc2[oy], 0, 0, 0);
            }
        }
    }

    const float4 bv = *(const float4*)&bias[co0 + quad * 4];
    const float bb[4] = {bv.x, bv.y, bv.z, bv.w};
#pragma unroll
    for (int oy = 0; oy < 4; oy++) {
        half4 hv, lv;
#pragma unroll
        for (int r = 0; r < 4; r++) {
            float v = acc1[oy][r] + acc2[oy][r] * (1.0f / 1024.0f) + bb[r];
            if (RELU) v = fmaxf(v, 0.f);
            _Float16 h = (_Float16)v;
            hv[r] = h;
            lv[r] = (_Float16)((v - (float)h) * 1024.f);
        }
        size_t o = (((size_t)img * OH + (oy0 + oy)) * OW + (ox0 + n16)) * COUT
                   + co0 + quad * 4;
        *(half4*)(outH + o) = hv;
        *(half4*)(outL + o) = lv;
    }
}

// ---------------------------------------------------------------------------
__global__ __launch_bounds__(64)
void cnorm_kernel(const float* __restrict__ cb, float* __restrict__ cn)
{
    const int code = blockIdx.x;
    const int t = threadIdx.x;
    const float* row = cb + (size_t)code * 512;
    float s = 0.f;
    for (int i = t; i < 512; i += 64) s += row[i] * row[i];
#pragma unroll
    for (int off = 32; off > 0; off >>= 1) s += __shfl_down(s, off, 64);
    if (t == 0) cn[code] = s;
}

__global__ __launch_bounds__(256)
void init_keys_kernel(unsigned long long* __restrict__ keys)
{
    keys[blockIdx.x * 256 + threadIdx.x] = ~0ull;
}

// ---------------------------------------------------------------------------
__global__ __launch_bounds__(256)
void split_cb_kernel(const float* __restrict__ cb,
                     _Float16* __restrict__ ch, _Float16* __restrict__ cl)
{
    size_t i = (size_t)blockIdx.x * 256 + threadIdx.x;
    float v = cb[i];
    _Float16 h = (_Float16)v;
    ch[i] = h;
    cl[i] = (_Float16)((v - (float)h) * 1024.f);
}

// ---------------------------------------------------------------------------
// VQ distance GEMM v2: fp16 split MFMA, codebook LDS double-buffered.
// Block 256 = 4 waves; tile 128 rows x 128 codes; wave = 32 rows x 128 codes.
// ---------------------------------------------------------------------------
__global__ __launch_bounds__(256)
void vq_mfma_kernel(const _Float16* __restrict__ zh, const _Float16* __restrict__ zl,
                    const _Float16* __restrict__ ch, const _Float16* __restrict__ cl,
                    const float* __restrict__ cn,
                    unsigned long long* __restrict__ keys)   // [16384]
{
    __shared__ _Float16 sB[2][2][128][40];   // [buf][plane][code][k-chunk pad 40]

    const int tid = threadIdx.x;
    const int lane = tid & 63;
    const int wave = tid >> 6;
    const int n16 = lane & 15;
    const int quad = lane >> 4;

    const int row0 = blockIdx.x * 128 + wave * 32;
    const int code0 = blockIdx.y * 128;

    floatx4 acc1[2][8], acc2[2][8];
#pragma unroll
    for (int rt = 0; rt < 2; rt++)
#pragma unroll
        for (int ct = 0; ct < 8; ct++) {
            acc1[rt][ct] = (floatx4){0.f, 0.f, 0.f, 0.f};
            acc2[rt][ct] = (floatx4){0.f, 0.f, 0.f, 0.f};
        }

    const _Float16* pzh = zh + (size_t)(row0 + n16) * 512 + quad * 8;
    const _Float16* pzl = zl + (size_t)(row0 + n16) * 512 + quad * 8;

    half8 As[2][4];
    // chunk 0: A frags + B stage
    As[0][0] = *(const half8*)(pzh);
    As[0][1] = *(const half8*)(pzh + 8192);
    As[0][2] = *(const half8*)(pzl);
    As[0][3] = *(const half8*)(pzl + 8192);
#pragma unroll
    for (int it = 0; it < 4; ++it) {
        int e = tid + it * 256;
        int pl = e >> 9, r = (e >> 2) & 127, q = e & 3;
        const _Float16* src = (pl ? cl : ch) + (size_t)(code0 + r) * 512 + q * 8;
        *(half8*)&sB[0][pl][r][q * 8] = *(const half8*)src;
    }
    __syncthreads();

#pragma unroll 2
    for (int c = 0; c < 16; ++c) {
        const int cur = c & 1;
        if (c < 15) {
            const int nxt = cur ^ 1;
            const int kk = (c + 1) * 32;
            As[nxt][0] = *(const half8*)(pzh + kk);
            As[nxt][1] = *(const half8*)(pzh + 8192 + kk);
            As[nxt][2] = *(const half8*)(pzl + kk);
            As[nxt][3] = *(const half8*)(pzl + 8192 + kk);
#pragma unroll
            for (int it = 0; it < 4; ++it) {
                int e = tid + it * 256;
                int pl = e >> 9, r = (e >> 2) & 127, q = e & 3;
                const _Float16* src = (pl ? cl : ch) + (size_t)(code0 + r) * 512 + kk + q * 8;
                *(half8*)&sB[nxt][pl][r][q * 8] = *(const half8*)src;
            }
        }
#pragma unroll
        for (int ct = 0; ct < 8; ++ct) {
            half8 bh = *(const half8*)&sB[cur][0][ct * 16 + n16][quad * 8];
            half8 bl = *(const half8*)&sB[cur][1][ct * 16 + n16][quad * 8];
            acc1[0][ct] = __builtin_amdgcn_mfma_f32_16x16x32_f16(As[cur][0], bh, acc1[0][ct], 0, 0, 0);
            acc1[1][ct] = __builtin_amdgcn_mfma_f32_16x16x32_f16(As[cur][1], bh, acc1[1][ct], 0, 0, 0);
            acc2[0][ct] = __builtin_amdgcn_mfma_f32_16x16x32_f16(As[cur][0], bl, acc2[0][ct], 0, 0, 0);
            acc2[1][ct] = __builtin_amdgcn_mfma_f32_16x16x32_f16(As[cur][1], bl, acc2[1][ct], 0, 0, 0);
            acc2[0][ct] = __builtin_amdgcn_mfma_f32_16x16x32_f16(As[cur][2], bh, acc2[0][ct], 0, 0, 0);
            acc2[1][ct] = __builtin_amdgcn_mfma_f32_16x16x32_f16(As[cur][3], bh, acc2[1][ct], 0, 0, 0);
        }
        __syncthreads();
    }

#pragma unroll
    for (int rt = 0; rt < 2; rt++) {
#pragma unroll
        for (int reg = 0; reg < 4; reg++) {
            float best = 3.0e38f;
            int bcode = 0;
#pragma unroll
            for (int ct = 0; ct < 8; ct++) {
                const int code = code0 + ct * 16 + n16;
                float dot = acc1[rt][ct][reg] + acc2[rt][ct][reg] * (1.0f / 1024.0f);
                float s = cn[code] - 2.0f * dot;
                if (s < best) { best = s; bcode = code; }
            }
            unsigned u = __float_as_uint(best);
            u = (u & 0x80000000u) ? ~u : (u | 0x80000000u);
            unsigned long long key = ((unsigned long long)u << 32) | (unsigned)bcode;
#pragma unroll
            for (int m = 1; m < 16; m <<= 1) {
                unsigned long long o = __shfl_xor(key, m, 64);
                key = (o < key) ? o : key;
            }
            if (n16 == 0)
                atomicMin(&keys[row0 + rt * 16 + quad * 4 + reg], key);
        }
    }
}

// ---------------------------------------------------------------------------
// Gather: indices (float) into d_out tail, zq as bf16 NHWC [16,32,32,512].
// ---------------------------------------------------------------------------
__global__ __launch_bounds__(256)
void vq_gather_kernel(const unsigned long long* __restrict__ keys,
                      const float* __restrict__ cb,
                      unsigned short* __restrict__ zq, float* __restrict__ idx_out)
{
    __shared__ int sidx[64];
    const int t = threadIdx.x;
    const int v0 = blockIdx.x * 64;
    if (t < 64) {
        int idx = (int)(keys[v0 + t] & 0xFFFFFFFFull);
        sidx[t] = idx;
        idx_out[v0 + t] = (float)idx;
    }
    __syncthreads();
    const int tv = t >> 2;
    const int q = t & 3;
    const float* crow = cb + (size_t)sidx[tv] * 512;
    unsigned short* zrow = zq + (size_t)(v0 + tv) * 512;
    for (int c = q * 8; c < 512; c += 32) {
        float4 f0 = *(const float4*)(crow + c);
        float4 f1 = *(const float4*)(crow + c + 4);
        short8 h;
        h[0] = (short)f2bf(f0.x); h[1] = (short)f2bf(f0.y);
        h[2] = (short)f2bf(f0.z); h[3] = (short)f2bf(f0.w);
        h[4] = (short)f2bf(f1.x); h[5] = (short)f2bf(f1.y);
        h[6] = (short)f2bf(f1.z); h[7] = (short)f2bf(f1.w);
        *(short8*)(zrow + c) = h;
    }
}

// ---------------------------------------------------------------------------
// Deconv weight prepack: torch [CI][CO][3][3] f32 -> [tap][CO][CI] bf16
// ---------------------------------------------------------------------------
template<int CI, int CO>
__global__ __launch_bounds__(256)
void prepack_kernel(const float* __restrict__ w, unsigned short* __restrict__ wp)
{
    int i = blockIdx.x * 256 + threadIdx.x;
    if (i >= 9 * CO * CI) return;
    int ci = i / (CO * 9);
    int r  = i % (CO * 9);
    int co = r / 9;
    int tp = r % 9;
    wp[((size_t)tp * CO + co) * CI + ci] = f2bf(w[i]);
}

// ---------------------------------------------------------------------------
// MFMA ConvTranspose2d k=3 s=2 p=1 op=1 + ReLU, bf16.
// ---------------------------------------------------------------------------
template<int CIN, int COUT, int IH, int IW, bool OUT_NCHW>
__global__ __launch_bounds__(256)
void deconv_mfma_kernel(const unsigned short* __restrict__ in,   // NHWC bf16
                        const unsigned short* __restrict__ wp,   // [9][CO][CI] bf16
                        const float* __restrict__ bias,
                        unsigned short* __restrict__ out)        // bf16
{
    constexpr int OH = 2 * IH, OW = 2 * IW;
    __shared__ short sIn[5][17][40];

    const int tid = threadIdx.x;
    const int lane = tid & 63;
    const int wave = tid >> 6;
    const int n16 = lane & 15;
    const int quad = lane >> 4;

    constexpr int NTX = IW / 16;
    const int x0 = (blockIdx.x % NTX) * 16;
    const int y0 = (blockIdx.x / NTX) * 4;
    const int co0 = blockIdx.y * 64 + wave * 16;
    const int img = blockIdx.z;

    const unsigned short* inN = in + (size_t)img * IH * IW * CIN;

    floatx4 acc[4][4];
#pragma unroll
    for (int s = 0; s < 4; s++)
#pragma unroll
        for (int c = 0; c < 4; c++) acc[s][c] = (floatx4){0.f, 0.f, 0.f, 0.f};

    for (int k0 = 0; k0 < CIN; k0 += 32) {
        __syncthreads();
        for (int e = tid; e < 340; e += 256) {
            int yy = e / 68, r = e % 68;
            int xx = r >> 2, q4 = r & 3;
            int gy = y0 + yy, gx = x0 + xx;
            short8 v = {0, 0, 0, 0, 0, 0, 0, 0};
            if (gy < IH && gx < IW)
                v = *(const short8*)(inN + ((size_t)(gy * IW + gx) * CIN + k0 + q4 * 8));
            *(short8*)&sIn[yy][xx][q4 * 8] = v;
        }
        __syncthreads();

        short8 a[9];
#pragma unroll
        for (int tp = 0; tp < 9; tp++)
            a[tp] = *(const short8*)(wp + ((size_t)(tp * COUT + co0 + n16) * CIN + k0 + quad * 8));

#pragma unroll
        for (int s = 0; s < 4; s++) {
            short8 b00 = *(const short8*)&sIn[s    ][n16    ][quad * 8];
            short8 b01 = *(const short8*)&sIn[s    ][n16 + 1][quad * 8];
            short8 b10 = *(const short8*)&sIn[s + 1][n16    ][quad * 8];
            short8 b11 = *(const short8*)&sIn[s + 1][n16 + 1][quad * 8];
            acc[s][0] = __builtin_amdgcn_mfma_f32_16x16x32_bf16(a[4], b00, acc[s][0], 0, 0, 0);
            acc[s][1] = __builtin_amdgcn_mfma_f32_16x16x32_bf16(a[3], b01, acc[s][1], 0, 0, 0);
            acc[s][1] = __builtin_amdgcn_mfma_f32_16x16x32_bf16(a[5], b00, acc[s][1], 0, 0, 0);
            acc[s][2] = __builtin_amdgcn_mfma_f32_16x16x32_bf16(a[1], b10, acc[s][2], 0, 0, 0);
            acc[s][2] = __builtin_amdgcn_mfma_f32_16x16x32_bf16(a[7], b00, acc[s][2], 0, 0, 0);
            acc[s][3] = __builtin_amdgcn_mfma_f32_16x16x32_bf16(a[0], b11, acc[s][3], 0, 0, 0);
            acc[s][3] = __builtin_amdgcn_mfma_f32_16x16x32_bf16(a[2], b10, acc[s][3], 0, 0, 0);
            acc[s][3] = __builtin_amdgcn_mfma_f32_16x16x32_bf16(a[6], b01, acc[s][3], 0, 0, 0);
            acc[s][3] = __builtin_amdgcn_mfma_f32_16x16x32_bf16(a[8], b00, acc[s][3], 0, 0, 0);
        }
    }

    const float4 bv = *(const float4*)&bias[co0 + quad * 4];
    const float bb[4] = {bv.x, bv.y, bv.z, bv.w};
    const int x = x0 + n16;

    if (!OUT_NCHW) {
        unsigned short* outN = out + (size_t)img * OH * OW * COUT;
#pragma unroll
        for (int s = 0; s < 4; s++) {
            const int y = y0 + s;
#pragma unroll
            for (int c = 0; c < 4; c++) {
                const int oy = 2 * y + (c >> 1);
                const int ox = 2 * x + (c & 1);
                ushort4 h;
                h.x = f2bf(fmaxf(acc[s][c][0] + bb[0], 0.f));
                h.y = f2bf(fmaxf(acc[s][c][1] + bb[1], 0.f));
                h.z = f2bf(fmaxf(acc[s][c][2] + bb[2], 0.f));
                h.w = f2bf(fmaxf(acc[s][c][3] + bb[3], 0.f));
                *(ushort4*)(outN + ((size_t)(oy * OW + ox) * COUT + co0 + quad * 4)) = h;
            }
        }
    } else {
#pragma unroll
        for (int s = 0; s < 4; s++) {
            const int y = y0 + s;
#pragma unroll
            for (int r = 0; r < 4; r++) {
                const int co = co0 + quad * 4 + r;
                unsigned short* oC = out + (size_t)(img * COUT + co) * OH * OW;
                unsigned p0 = (unsigned)f2bf(fmaxf(acc[s][0][r] + bb[r], 0.f)) |
                              ((unsigned)f2bf(fmaxf(acc[s][1][r] + bb[r], 0.f)) << 16);
                unsigned p1 = (unsigned)f2bf(fmaxf(acc[s][2][r] + bb[r], 0.f)) |
                              ((unsigned)f2bf(fmaxf(acc[s][3][r] + bb[r], 0.f)) << 16);
                *(unsigned*)(oC + (size_t)(2 * y) * OW + 2 * x) = p0;
                *(unsigned*)(oC + (size_t)(2 * y + 1) * OW + 2 * x) = p1;
            }
        }
    }
}

// ---------------------------------------------------------------------------
// Final conv 64->3 + sigmoid. NCHW bf16 input, fp32 out (d_out).
// ---------------------------------------------------------------------------
__global__ __launch_bounds__(256)
void conv_out_kernel(const unsigned short* __restrict__ in, // [16,64,256,256] bf16
                     const float* __restrict__ w,           // [3,64,3,3]
                     const float* __restrict__ bias,
                     float* __restrict__ out)               // [16,3,256,256]
{
    constexpr int TIC = 4;
    __shared__ float s_in[TIC][3][258];
    const int t = threadIdx.x;
    const int y = blockIdx.x;
    const int n = blockIdx.y;
    const unsigned short* inN = in + (size_t)n * 64 * 65536;
    float acc0 = bias[0], acc1 = bias[1], acc2 = bias[2];

    for (int c0 = 0; c0 < 64; c0 += TIC) {
        for (int e = t; e < TIC * 3 * 258; e += 256) {
            int ci = e / 774;
            int r  = e % 774;
            int ry = r / 258, xx = r % 258;
            int gy = y - 1 + ry, gx = xx - 1;
            float v = 0.f;
            if ((unsigned)gy < 256u && (unsigned)gx < 256u)
                v = bf2f(inN[(size_t)(c0 + ci) * 65536 + gy * 256 + gx]);
            s_in[ci][ry][xx] = v;
        }
        __syncthreads();
#pragma unroll
        for (int ci = 0; ci < TIC; ++ci) {
            float iv[3][3];
#pragma unroll
            for (int ry = 0; ry < 3; ry++)
#pragma unroll
                for (int kx = 0; kx < 3; kx++)
                    iv[ry][kx] = s_in[ci][ry][t + kx];
#pragma unroll
            for (int k = 0; k < 9; k++) {
                const float v = iv[k / 3][k % 3];
                acc0 += w[(0 * 64 + c0 + ci) * 9 + k] * v;
                acc1 += w[(1 * 64 + c0 + ci) * 9 + k] * v;
                acc2 += w[(2 * 64 + c0 + ci) * 9 + k] * v;
            }
        }
        __syncthreads();
    }
    const size_t o = (size_t)((n * 3 + 0) * 256 + y) * 256 + t;
    out[o]          = 1.f / (1.f + __expf(-acc0));
    out[o + 65536]  = 1.f / (1.f + __expf(-acc1));
    out[o + 131072] = 1.f / (1.f + __expf(-acc2));
}

// ---------------------------------------------------------------------------
// Workspace (peak 201.5 MB):
//  H2h [0,67.1M)  H2l [67.1,134.2M)     (NHWC fp16, dead after conv3)
//  H3h [134.2,167.8M)  H3l [167.8,201.3M)  (dead after conv4)
//  ZH [0,16.8M)  ZL [16.8,33.5M)  ZQ [33.5,50.3M)
//  CBH [50.3,58.7M)  CBL [58.7,67.1M)   (over dead H2h tail)
//  G1 [67.1,83.9M) over dead H2l ; G2 [134.2,167.8M) over dead H3
//  G3 [0,134.2M) (all prior region-0 tenants dead)
//  keys @201.3M (128K) + cn (32K)
// d_out head (overwritten by conv_out): EW3h/l, EW4h/l, WP1, WP2, WP3
// ---------------------------------------------------------------------------
extern "C" void kernel_launch(void* const* d_in, const int* in_sizes, int n_in,
                              void* d_out, int out_size, void* d_ws, size_t ws_size,
                              hipStream_t stream)
{
    const float* x   = (const float*)d_in[0];
    const float* w1  = (const float*)d_in[1];
    const float* b1  = (const float*)d_in[2];
    const float* w2  = (const float*)d_in[3];
    const float* b2  = (const float*)d_in[4];
    const float* w3  = (const float*)d_in[5];
    const float* b3  = (const float*)d_in[6];
    const float* w4  = (const float*)d_in[7];
    const float* b4  = (const float*)d_in[8];
    const float* cb  = (const float*)d_in[9];
    const float* d1w = (const float*)d_in[10];
    const float* d1b = (const float*)d_in[11];
    const float* d2w = (const float*)d_in[12];
    const float* d2b = (const float*)d_in[13];
    const float* d3w = (const float*)d_in[14];
    const float* d3b = (const float*)d_in[15];
    const float* wo  = (const float*)d_in[16];
    const float* bo  = (const float*)d_in[17];

    char* ws = (char*)d_ws;
    _Float16* H2H = (_Float16*)(ws);
    _Float16* H2L = (_Float16*)(ws + 67108864);
    _Float16* H3H = (_Float16*)(ws + 134217728);
    _Float16* H3L = (_Float16*)(ws + 167772160);
    _Float16* ZH  = (_Float16*)(ws);
    _Float16* ZL  = (_Float16*)(ws + 16777216);
    unsigned short* ZQ = (unsigned short*)(ws + 33554432);
    _Float16* CBH = (_Float16*)(ws + 50331648);
    _Float16* CBL = (_Float16*)(ws + 58720256);
    unsigned short* G1 = (unsigned short*)(ws + 67108864);
    unsigned short* G2 = (unsigned short*)(ws + 134217728);
    unsigned short* G3 = (unsigned short*)(ws);
    unsigned long long* keys = (unsigned long long*)(ws + 201326592);
    float* cn = (float*)(ws + 201326592 + 131072);

    // d_out head as prepack scratch (fully overwritten by conv_out at the end)
    char* oscratch = (char*)d_out;
    _Float16* EW3H = (_Float16*)(oscratch);
    _Float16* EW3L = (_Float16*)(oscratch + 589824);
    _Float16* EW4H = (_Float16*)(oscratch + 1179648);
    _Float16* EW4L = (_Float16*)(oscratch + 3538944);
    unsigned short* WP1 = (unsigned short*)(oscratch + 5898240);
    unsigned short* WP2 = (unsigned short*)(oscratch + 8257536);
    unsigned short* WP3 = (unsigned short*)(oscratch + 8847360);

    float* xrec = (float*)d_out;
    float* idxf = (float*)d_out + (size_t)16 * 3 * 256 * 256;

    // ---- weight prepacks ----
    prepack_conv_kernel<128, 256><<<1152, 256, 0, stream>>>(w3, EW3H, EW3L);
    prepack_conv_kernel<256, 512><<<4608, 256, 0, stream>>>(w4, EW4H, EW4L);
    prepack_kernel<512, 256><<<4608, 256, 0, stream>>>(d1w, WP1);
    prepack_kernel<256, 128><<<1152, 256, 0, stream>>>(d2w, WP2);
    prepack_kernel<128, 64 ><<<288,  256, 0, stream>>>(d3w, WP3);

    // ---- encoder ----
    fused_conv12_kernel<<<dim3(128, 2, 16), 256, 0, stream>>>(x, w1, b1, w2, b2, H2H, H2L);
    conv_mfma_kernel<128, 256, 128, 128, true ><<<dim3(64, 4, 16), 256, 0, stream>>>(H2H, H2L, EW3H, EW3L, b3, H3H, H3L);
    conv_mfma_kernel<256, 512, 64,  64,  false><<<dim3(16, 8, 16), 256, 0, stream>>>(H3H, H3L, EW4H, EW4L, b4, ZH, ZL);

    // ---- VQ ----
    cnorm_kernel<<<8192, 64, 0, stream>>>(cb, cn);
    init_keys_kernel<<<64, 256, 0, stream>>>(keys);
    split_cb_kernel<<<16384, 256, 0, stream>>>(cb, CBH, CBL);
    vq_mfma_kernel<<<dim3(128, 64), 256, 0, stream>>>(ZH, ZL, CBH, CBL, cn, keys);
    vq_gather_kernel<<<256, 256, 0, stream>>>(keys, cb, ZQ, idxf);

    // ---- decoder (bf16 MFMA) ----
    deconv_mfma_kernel<512, 256, 32,  32,  false><<<dim3(16,  4, 16), 256, 0, stream>>>(ZQ, WP1, d1b, G1);
    deconv_mfma_kernel<256, 128, 64,  64,  false><<<dim3(64,  2, 16), 256, 0, stream>>>(G1, WP2, d2b, G2);
    deconv_mfma_kernel<128, 64,  128, 128, true ><<<dim3(256, 1, 16), 256, 0, stream>>>(G2, WP3, d3b, G3);
    conv_out_kernel<<<dim3(256, 16), 256, 0, stream>>>(G3, wo, bo, xrec);
}

// Round 7
// 2332.310 us; speedup vs baseline: 10.9962x; 1.3414x over previous
//
#include <hip/hip_runtime.h>
#include <cstddef>

typedef short short8 __attribute__((ext_vector_type(8)));
typedef _Float16 half8 __attribute__((ext_vector_type(8)));
typedef _Float16 half4 __attribute__((ext_vector_type(4)));
typedef _Float16 half2v __attribute__((ext_vector_type(2)));
typedef float floatx4 __attribute__((ext_vector_type(4)));

// ---- bf16 helpers (round-to-nearest-even) ---------------------------------
__device__ __forceinline__ unsigned short f2bf(float f) {
    unsigned u = __float_as_uint(f);
    u += 0x7FFFu + ((u >> 16) & 1u);
    return (unsigned short)(u >> 16);
}
__device__ __forceinline__ float bf2f(unsigned short h) {
    return __uint_as_float((unsigned)h << 16);
}

// ---------------------------------------------------------------------------
// Fused conv1(3->64,s1,relu) + conv2(64->128,s2,relu) v2:
// conv1 inline fp32 (rolling x-window regs), conv2 split-fp16 MFMA.
// Block 256 = 4 waves (16 co each); output tile 16 ox x 4 oy.
// h1 patch 9x33x64 computed per ci-chunk(32) into hi/lo even/odd-x LDS.
// ---------------------------------------------------------------------------
__global__ __launch_bounds__(256)
void fused_conv12_mfma_kernel(const float* __restrict__ x,   // [16,3,256,256]
                              const float* __restrict__ w1,  // [64,3,3,3]
                              const float* __restrict__ b1,
                              const _Float16* __restrict__ w2h, // [9][128][64]
                              const _Float16* __restrict__ w2l,
                              const float* __restrict__ b2,
                              _Float16* __restrict__ outH,   // NHWC [16,128,128,128]
                              _Float16* __restrict__ outL)
{
    __shared__ float s_x[3][11][36];
    __shared__ _Float16 sE[2][9][17][40];   // [plane][row][x/2][ci pad 40]
    __shared__ _Float16 sO[2][9][16][40];

    const int tid = threadIdx.x;
    const int lane = tid & 63;
    const int wave = tid >> 6;
    const int n16 = lane & 15;
    const int quad = lane >> 4;

    const int ox0 = (blockIdx.x & 7) * 16;    // 128/16
    const int oy0 = (blockIdx.x >> 3) * 4;    // 32 y-tiles
    const int co0 = blockIdx.y * 64 + wave * 16;
    const int img = blockIdx.z;

    const int hy0 = oy0 * 2 - 1, hx0 = ox0 * 2 - 1;   // h1 tile origin (9x33)
    const int gy0 = hy0 - 1,     gx0 = hx0 - 1;       // x patch origin (11x35)
    const float* xN = x + (size_t)img * 3 * 65536;

    // stage x patch (once)
    for (int e = tid; e < 3 * 11 * 35; e += 256) {
        int c = e / 385, r = e % 385;
        int yy = r / 35, xx = r % 35;
        int gy = gy0 + yy, gx = gx0 + xx;
        float v = 0.f;
        if ((unsigned)gy < 256u && (unsigned)gx < 256u)
            v = xN[(size_t)c * 65536 + gy * 256 + gx];
        s_x[c][yy][xx] = v;
    }

    floatx4 acc1[4], acc2[4];
#pragma unroll
    for (int s = 0; s < 4; s++) {
        acc1[s] = (floatx4){0.f, 0.f, 0.f, 0.f};
        acc2[s] = (floatx4){0.f, 0.f, 0.f, 0.f};
    }

    const int pair = tid & 15;
    const int pxg  = tid >> 4;

    for (int c0 = 0; c0 < 64; c0 += 32) {
        __syncthreads();   // covers x staging (first iter) + prior MFMA readers

        // conv1: this thread owns 2 channels, x-strips {pxg, pxg+16, pxg+32}
        const int ch0 = c0 + pair * 2;
        float wA[27], wB[27];
#pragma unroll
        for (int k = 0; k < 27; k++) {
            wA[k] = w1[ch0 * 27 + k];
            wB[k] = w1[ch0 * 27 + 27 + k];
        }
        const float bA = b1[ch0], bB = b1[ch0 + 1];

        for (int px = pxg; px < 33; px += 16) {
            const bool colok = (unsigned)(hx0 + px) < 256u;
            float xw[3][3][3];   // [c][ky][kx] rolling window rows py..py+2
#pragma unroll
            for (int c = 0; c < 3; c++)
#pragma unroll
                for (int r = 0; r < 3; r++)
#pragma unroll
                    for (int kx = 0; kx < 3; kx++)
                        xw[c][r][kx] = s_x[c][r][px + kx];
#pragma unroll
            for (int py = 0; py < 9; py++) {
                const bool inb = colok && (unsigned)(hy0 + py) < 256u;
                float aA = bA, aB = bB;
#pragma unroll
                for (int c = 0; c < 3; c++)
#pragma unroll
                    for (int k = 0; k < 9; k++) {
                        const float xv = xw[c][k / 3][k % 3];
                        aA += wA[c * 9 + k] * xv;
                        aB += wB[c * 9 + k] * xv;
                    }
                float vA = inb ? fmaxf(aA, 0.f) : 0.f;
                float vB = inb ? fmaxf(aB, 0.f) : 0.f;
                half2v hv, lv;
                _Float16 hA = (_Float16)vA, hB = (_Float16)vB;
                hv[0] = hA; hv[1] = hB;
                lv[0] = (_Float16)((vA - (float)hA) * 1024.f);
                lv[1] = (_Float16)((vB - (float)hB) * 1024.f);
                _Float16* dH = (px & 1) ? &sO[0][py][px >> 1][pair * 2]
                                        : &sE[0][py][px >> 1][pair * 2];
                _Float16* dL = (px & 1) ? &sO[1][py][px >> 1][pair * 2]
                                        : &sE[1][py][px >> 1][pair * 2];
                *(half2v*)dH = hv;
                *(half2v*)dL = lv;
                if (py < 8) {
#pragma unroll
                    for (int c = 0; c < 3; c++) {
#pragma unroll
                        for (int r = 0; r < 2; r++)
#pragma unroll
                            for (int kx = 0; kx < 3; kx++)
                                xw[c][r][kx] = xw[c][r + 1][kx];
#pragma unroll
                        for (int kx = 0; kx < 3; kx++)
                            xw[c][2][kx] = s_x[c][py + 3][px + kx];
                    }
                }
            }
        }
        __syncthreads();

        // conv2 MFMA (split-precision fp16)
        half8 ah[9], al[9];
#pragma unroll
        for (int tp = 0; tp < 9; tp++) {
            size_t o = ((size_t)(tp * 128 + co0 + n16)) * 64 + c0 + quad * 8;
            ah[tp] = *(const half8*)(w2h + o);
            al[tp] = *(const half8*)(w2l + o);
        }
#pragma unroll
        for (int oy = 0; oy < 4; oy++) {
#pragma unroll
            for (int tp = 0; tp < 9; tp++) {
                const int kx = tp % 3;
                const int row = oy * 2 + tp / 3;
                half8 bh, bl;
                if (kx == 0)      { bh = *(const half8*)&sE[0][row][n16][quad * 8];
                                    bl = *(const half8*)&sE[1][row][n16][quad * 8]; }
                else if (kx == 1) { bh = *(const half8*)&sO[0][row][n16][quad * 8];
                                    bl = *(const half8*)&sO[1][row][n16][quad * 8]; }
                else              { bh = *(const half8*)&sE[0][row][n16 + 1][quad * 8];
                                    bl = *(const half8*)&sE[1][row][n16 + 1][quad * 8]; }
                acc1[oy] = __builtin_amdgcn_mfma_f32_16x16x32_f16(ah[tp], bh, acc1[oy], 0, 0, 0);
                acc2[oy] = __builtin_amdgcn_mfma_f32_16x16x32_f16(ah[tp], bl, acc2[oy], 0, 0, 0);
                acc2[oy] = __builtin_amdgcn_mfma_f32_16x16x32_f16(al[tp], bh, acc2[oy], 0, 0, 0);
            }
        }
    }

    const float4 bv = *(const float4*)&b2[co0 + quad * 4];
    const float bb[4] = {bv.x, bv.y, bv.z, bv.w};
#pragma unroll
    for (int oy = 0; oy < 4; oy++) {
        half4 hv, lv;
#pragma unroll
        for (int r = 0; r < 4; r++) {
            float v = fmaxf(acc1[oy][r] + acc2[oy][r] * (1.0f / 1024.0f) + bb[r], 0.f);
            _Float16 h = (_Float16)v;
            hv[r] = h;
            lv[r] = (_Float16)((v - (float)h) * 1024.f);
        }
        size_t o = (((size_t)img * 128 + (oy0 + oy)) * 128 + (ox0 + n16)) * 128
                   + co0 + quad * 4;
        *(half4*)(outH + o) = hv;
        *(half4*)(outL + o) = lv;
    }
}

// ---------------------------------------------------------------------------
// Encoder conv weight prepack: OIHW f32 -> [tap][CO][CI] fp16 hi + lo*1024
// ---------------------------------------------------------------------------
template<int CI, int CO>
__global__ __launch_bounds__(256)
void prepack_conv_kernel(const float* __restrict__ w,
                         _Float16* __restrict__ wh, _Float16* __restrict__ wl)
{
    int i = blockIdx.x * 256 + threadIdx.x;
    if (i >= CO * CI * 9) return;
    int co = i / (CI * 9);
    int r  = i % (CI * 9);
    int ci = r / 9;
    int tp = r % 9;
    float v = w[i];
    _Float16 h = (_Float16)v;
    size_t o = ((size_t)tp * CO + co) * CI + ci;
    wh[o] = h;
    wl[o] = (_Float16)((v - (float)h) * 1024.f);
}

// ---------------------------------------------------------------------------
// Split-precision fp16 MFMA 3x3 conv, stride 2, pad 1.  NHWC hi/lo in & out.
// ---------------------------------------------------------------------------
template<int CIN, int COUT, int IH, int IW, bool RELU>
__global__ __launch_bounds__(256)
void conv_mfma_kernel(const _Float16* __restrict__ inH, const _Float16* __restrict__ inL,
                      const _Float16* __restrict__ wpH, const _Float16* __restrict__ wpL,
                      const float* __restrict__ bias,
                      _Float16* __restrict__ outH, _Float16* __restrict__ outL)
{
    constexpr int OH = IH / 2, OW = IW / 2;
    __shared__ _Float16 sE[2][9][17][40];
    __shared__ _Float16 sO[2][9][16][40];

    const int tid = threadIdx.x;
    const int lane = tid & 63;
    const int wave = tid >> 6;
    const int n16 = lane & 15;
    const int quad = lane >> 4;

    constexpr int NTX = OW / 16;
    const int ox0 = (blockIdx.x % NTX) * 16;
    const int oy0 = (blockIdx.x / NTX) * 4;
    const int co0 = blockIdx.y * 64 + wave * 16;
    const int img = blockIdx.z;

    const int iy0 = oy0 * 2 - 1;
    const int ix0 = ox0 * 2 - 1;
    const _Float16* iNH = inH + (size_t)img * IH * IW * CIN;
    const _Float16* iNL = inL + (size_t)img * IH * IW * CIN;

    floatx4 acc1[4], acc2[4];
#pragma unroll
    for (int s = 0; s < 4; s++) {
        acc1[s] = (floatx4){0.f, 0.f, 0.f, 0.f};
        acc2[s] = (floatx4){0.f, 0.f, 0.f, 0.f};
    }

    for (int k0 = 0; k0 < CIN; k0 += 32) {
        __syncthreads();
        for (int e = tid; e < 2376; e += 256) {
            int pl = e / 1188;
            int r  = e % 1188;
            int pix = r >> 2, q = r & 3;
            int py = pix / 33, px = pix % 33;
            int iy = iy0 + py, ix = ix0 + px;
            half8 v = (half8)(_Float16)0;
            if ((unsigned)iy < (unsigned)IH && (unsigned)ix < (unsigned)IW)
                v = *(const half8*)((pl ? iNL : iNH) + ((size_t)(iy * IW + ix) * CIN + k0 + q * 8));
            if (px & 1) *(half8*)&sO[pl][py][px >> 1][q * 8] = v;
            else        *(half8*)&sE[pl][py][px >> 1][q * 8] = v;
        }
        __syncthreads();

        half8 ah[9], al[9];
#pragma unroll
        for (int tp = 0; tp < 9; tp++) {
            size_t o = ((size_t)(tp * COUT + co0 + n16)) * CIN + k0 + quad * 8;
            ah[tp] = *(const half8*)(wpH + o);
            al[tp] = *(const half8*)(wpL + o);
        }

#pragma unroll
        for (int oy = 0; oy < 4; oy++) {
#pragma unroll
            for (int tp = 0; tp < 9; tp++) {
                const int ky = tp / 3, kx = tp % 3;
                const int row = oy * 2 + ky;
                half8 bh, bl;
                if (kx == 0)      { bh = *(const half8*)&sE[0][row][n16][quad * 8];
                                    bl = *(const half8*)&sE[1][row][n16][quad * 8]; }
                else if (kx == 1) { bh = *(const half8*)&sO[0][row][n16][quad * 8];
                                    bl = *(const half8*)&sO[1][row][n16][quad * 8]; }
                else              { bh = *(const half8*)&sE[0][row][n16 + 1][quad * 8];
                                    bl = *(const half8*)&sE[1][row][n16 + 1][quad * 8]; }
                acc1[oy] = __builtin_amdgcn_mfma_f32_16x16x32_f16(ah[tp], bh, acc1[oy], 0, 0, 0);
                acc2[oy] = __builtin_amdgcn_mfma_f32_16x16x32_f16(ah[tp], bl, acc2[oy], 0, 0, 0);
                acc2[oy] = __builtin_amdgcn_mfma_f32_16x16x32_f16(al[tp], bh, acc2[oy], 0, 0, 0);
            }
        }
    }

    const float4 bv = *(const float4*)&bias[co0 + quad * 4];
    const float bb[4] = {bv.x, bv.y, bv.z, bv.w};
#pragma unroll
    for (int oy = 0; oy < 4; oy++) {
        half4 hv, lv;
#pragma unroll
        for (int r = 0; r < 4; r++) {
            float v = acc1[oy][r] + acc2[oy][r] * (1.0f / 1024.0f) + bb[r];
            if (RELU) v = fmaxf(v, 0.f);
            _Float16 h = (_Float16)v;
            hv[r] = h;
            lv[r] = (_Float16)((v - (float)h) * 1024.f);
        }
        size_t o = (((size_t)img * OH + (oy0 + oy)) * OW + (ox0 + n16)) * COUT
                   + co0 + quad * 4;
        *(half4*)(outH + o) = hv;
        *(half4*)(outL + o) = lv;
    }
}

// ---------------------------------------------------------------------------
__global__ __launch_bounds__(64)
void cnorm_kernel(const float* __restrict__ cb, float* __restrict__ cn)
{
    const int code = blockIdx.x;
    const int t = threadIdx.x;
    const float* row = cb + (size_t)code * 512;
    float s = 0.f;
    for (int i = t; i < 512; i += 64) s += row[i] * row[i];
#pragma unroll
    for (int off = 32; off > 0; off >>= 1) s += __shfl_down(s, off, 64);
    if (t == 0) cn[code] = s;
}

__global__ __launch_bounds__(256)
void init_keys_kernel(unsigned long long* __restrict__ keys)
{
    keys[blockIdx.x * 256 + threadIdx.x] = ~0ull;
}

// ---------------------------------------------------------------------------
__global__ __launch_bounds__(256)
void split_cb_kernel(const float* __restrict__ cb,
                     _Float16* __restrict__ ch, _Float16* __restrict__ cl)
{
    size_t i = (size_t)blockIdx.x * 256 + threadIdx.x;
    float v = cb[i];
    _Float16 h = (_Float16)v;
    ch[i] = h;
    cl[i] = (_Float16)((v - (float)h) * 1024.f);
}

// ---------------------------------------------------------------------------
// VQ distance GEMM: fp16 split MFMA, codebook LDS double-buffered.
// ---------------------------------------------------------------------------
__global__ __launch_bounds__(256)
void vq_mfma_kernel(const _Float16* __restrict__ zh, const _Float16* __restrict__ zl,
                    const _Float16* __restrict__ ch, const _Float16* __restrict__ cl,
                    const float* __restrict__ cn,
                    unsigned long long* __restrict__ keys)   // [16384]
{
    __shared__ _Float16 sB[2][2][128][40];

    const int tid = threadIdx.x;
    const int lane = tid & 63;
    const int wave = tid >> 6;
    const int n16 = lane & 15;
    const int quad = lane >> 4;

    const int row0 = blockIdx.x * 128 + wave * 32;
    const int code0 = blockIdx.y * 128;

    floatx4 acc1[2][8], acc2[2][8];
#pragma unroll
    for (int rt = 0; rt < 2; rt++)
#pragma unroll
        for (int ct = 0; ct < 8; ct++) {
            acc1[rt][ct] = (floatx4){0.f, 0.f, 0.f, 0.f};
            acc2[rt][ct] = (floatx4){0.f, 0.f, 0.f, 0.f};
        }

    const _Float16* pzh = zh + (size_t)(row0 + n16) * 512 + quad * 8;
    const _Float16* pzl = zl + (size_t)(row0 + n16) * 512 + quad * 8;

    half8 As[2][4];
    As[0][0] = *(const half8*)(pzh);
    As[0][1] = *(const half8*)(pzh + 8192);
    As[0][2] = *(const half8*)(pzl);
    As[0][3] = *(const half8*)(pzl + 8192);
#pragma unroll
    for (int it = 0; it < 4; ++it) {
        int e = tid + it * 256;
        int pl = e >> 9, r = (e >> 2) & 127, q = e & 3;
        const _Float16* src = (pl ? cl : ch) + (size_t)(code0 + r) * 512 + q * 8;
        *(half8*)&sB[0][pl][r][q * 8] = *(const half8*)src;
    }
    __syncthreads();

#pragma unroll 2
    for (int c = 0; c < 16; ++c) {
        const int cur = c & 1;
        if (c < 15) {
            const int nxt = cur ^ 1;
            const int kk = (c + 1) * 32;
            As[nxt][0] = *(const half8*)(pzh + kk);
            As[nxt][1] = *(const half8*)(pzh + 8192 + kk);
            As[nxt][2] = *(const half8*)(pzl + kk);
            As[nxt][3] = *(const half8*)(pzl + 8192 + kk);
#pragma unroll
            for (int it = 0; it < 4; ++it) {
                int e = tid + it * 256;
                int pl = e >> 9, r = (e >> 2) & 127, q = e & 3;
                const _Float16* src = (pl ? cl : ch) + (size_t)(code0 + r) * 512 + kk + q * 8;
                *(half8*)&sB[nxt][pl][r][q * 8] = *(const half8*)src;
            }
        }
#pragma unroll
        for (int ct = 0; ct < 8; ++ct) {
            half8 bh = *(const half8*)&sB[cur][0][ct * 16 + n16][quad * 8];
            half8 bl = *(const half8*)&sB[cur][1][ct * 16 + n16][quad * 8];
            acc1[0][ct] = __builtin_amdgcn_mfma_f32_16x16x32_f16(As[cur][0], bh, acc1[0][ct], 0, 0, 0);
            acc1[1][ct] = __builtin_amdgcn_mfma_f32_16x16x32_f16(As[cur][1], bh, acc1[1][ct], 0, 0, 0);
            acc2[0][ct] = __builtin_amdgcn_mfma_f32_16x16x32_f16(As[cur][0], bl, acc2[0][ct], 0, 0, 0);
            acc2[1][ct] = __builtin_amdgcn_mfma_f32_16x16x32_f16(As[cur][1], bl, acc2[1][ct], 0, 0, 0);
            acc2[0][ct] = __builtin_amdgcn_mfma_f32_16x16x32_f16(As[cur][2], bh, acc2[0][ct], 0, 0, 0);
            acc2[1][ct] = __builtin_amdgcn_mfma_f32_16x16x32_f16(As[cur][3], bh, acc2[1][ct], 0, 0, 0);
        }
        __syncthreads();
    }

#pragma unroll
    for (int rt = 0; rt < 2; rt++) {
#pragma unroll
        for (int reg = 0; reg < 4; reg++) {
            float best = 3.0e38f;
            int bcode = 0;
#pragma unroll
            for (int ct = 0; ct < 8; ct++) {
                const int code = code0 + ct * 16 + n16;
                float dot = acc1[rt][ct][reg] + acc2[rt][ct][reg] * (1.0f / 1024.0f);
                float s = cn[code] - 2.0f * dot;
                if (s < best) { best = s; bcode = code; }
            }
            unsigned u = __float_as_uint(best);
            u = (u & 0x80000000u) ? ~u : (u | 0x80000000u);
            unsigned long long key = ((unsigned long long)u << 32) | (unsigned)bcode;
#pragma unroll
            for (int m = 1; m < 16; m <<= 1) {
                unsigned long long o = __shfl_xor(key, m, 64);
                key = (o < key) ? o : key;
            }
            if (n16 == 0)
                atomicMin(&keys[row0 + rt * 16 + quad * 4 + reg], key);
        }
    }
}

// ---------------------------------------------------------------------------
// Gather: indices (float) into d_out tail, zq as bf16 NHWC [16,32,32,512].
// ---------------------------------------------------------------------------
__global__ __launch_bounds__(256)
void vq_gather_kernel(const unsigned long long* __restrict__ keys,
                      const float* __restrict__ cb,
                      unsigned short* __restrict__ zq, float* __restrict__ idx_out)
{
    __shared__ int sidx[64];
    const int t = threadIdx.x;
    const int v0 = blockIdx.x * 64;
    if (t < 64) {
        int idx = (int)(keys[v0 + t] & 0xFFFFFFFFull);
        sidx[t] = idx;
        idx_out[v0 + t] = (float)idx;
    }
    __syncthreads();
    const int tv = t >> 2;
    const int q = t & 3;
    const float* crow = cb + (size_t)sidx[tv] * 512;
    unsigned short* zrow = zq + (size_t)(v0 + tv) * 512;
    for (int c = q * 8; c < 512; c += 32) {
        float4 f0 = *(const float4*)(crow + c);
        float4 f1 = *(const float4*)(crow + c + 4);
        short8 h;
        h[0] = (short)f2bf(f0.x); h[1] = (short)f2bf(f0.y);
        h[2] = (short)f2bf(f0.z); h[3] = (short)f2bf(f0.w);
        h[4] = (short)f2bf(f1.x); h[5] = (short)f2bf(f1.y);
        h[6] = (short)f2bf(f1.z); h[7] = (short)f2bf(f1.w);
        *(short8*)(zrow + c) = h;
    }
}

// ---------------------------------------------------------------------------
// Deconv weight prepack: torch [CI][CO][3][3] f32 -> [tap][CO][CI] bf16
// ---------------------------------------------------------------------------
template<int CI, int CO>
__global__ __launch_bounds__(256)
void prepack_kernel(const float* __restrict__ w, unsigned short* __restrict__ wp)
{
    int i = blockIdx.x * 256 + threadIdx.x;
    if (i >= 9 * CO * CI) return;
    int ci = i / (CO * 9);
    int r  = i % (CO * 9);
    int co = r / 9;
    int tp = r % 9;
    wp[((size_t)tp * CO + co) * CI + ci] = f2bf(w[i]);
}

// ---------------------------------------------------------------------------
// MFMA ConvTranspose2d k=3 s=2 p=1 op=1 + ReLU, bf16.
// ---------------------------------------------------------------------------
template<int CIN, int COUT, int IH, int IW, bool OUT_NCHW>
__global__ __launch_bounds__(256)
void deconv_mfma_kernel(const unsigned short* __restrict__ in,   // NHWC bf16
                        const unsigned short* __restrict__ wp,   // [9][CO][CI] bf16
                        const float* __restrict__ bias,
                        unsigned short* __restrict__ out)        // bf16
{
    constexpr int OH = 2 * IH, OW = 2 * IW;
    __shared__ short sIn[5][17][40];

    const int tid = threadIdx.x;
    const int lane = tid & 63;
    const int wave = tid >> 6;
    const int n16 = lane & 15;
    const int quad = lane >> 4;

    constexpr int NTX = IW / 16;
    const int x0 = (blockIdx.x % NTX) * 16;
    const int y0 = (blockIdx.x / NTX) * 4;
    const int co0 = blockIdx.y * 64 + wave * 16;
    const int img = blockIdx.z;

    const unsigned short* inN = in + (size_t)img * IH * IW * CIN;

    floatx4 acc[4][4];
#pragma unroll
    for (int s = 0; s < 4; s++)
#pragma unroll
        for (int c = 0; c < 4; c++) acc[s][c] = (floatx4){0.f, 0.f, 0.f, 0.f};

    for (int k0 = 0; k0 < CIN; k0 += 32) {
        __syncthreads();
        for (int e = tid; e < 340; e += 256) {
            int yy = e / 68, r = e % 68;
            int xx = r >> 2, q4 = r & 3;
            int gy = y0 + yy, gx = x0 + xx;
            short8 v = {0, 0, 0, 0, 0, 0, 0, 0};
            if (gy < IH && gx < IW)
                v = *(const short8*)(inN + ((size_t)(gy * IW + gx) * CIN + k0 + q4 * 8));
            *(short8*)&sIn[yy][xx][q4 * 8] = v;
        }
        __syncthreads();

        short8 a[9];
#pragma unroll
        for (int tp = 0; tp < 9; tp++)
            a[tp] = *(const short8*)(wp + ((size_t)(tp * COUT + co0 + n16) * CIN + k0 + quad * 8));

#pragma unroll
        for (int s = 0; s < 4; s++) {
            short8 b00 = *(const short8*)&sIn[s    ][n16    ][quad * 8];
            short8 b01 = *(const short8*)&sIn[s    ][n16 + 1][quad * 8];
            short8 b10 = *(const short8*)&sIn[s + 1][n16    ][quad * 8];
            short8 b11 = *(const short8*)&sIn[s + 1][n16 + 1][quad * 8];
            acc[s][0] = __builtin_amdgcn_mfma_f32_16x16x32_bf16(a[4], b00, acc[s][0], 0, 0, 0);
            acc[s][1] = __builtin_amdgcn_mfma_f32_16x16x32_bf16(a[3], b01, acc[s][1], 0, 0, 0);
            acc[s][1] = __builtin_amdgcn_mfma_f32_16x16x32_bf16(a[5], b00, acc[s][1], 0, 0, 0);
            acc[s][2] = __builtin_amdgcn_mfma_f32_16x16x32_bf16(a[1], b10, acc[s][2], 0, 0, 0);
            acc[s][2] = __builtin_amdgcn_mfma_f32_16x16x32_bf16(a[7], b00, acc[s][2], 0, 0, 0);
            acc[s][3] = __builtin_amdgcn_mfma_f32_16x16x32_bf16(a[0], b11, acc[s][3], 0, 0, 0);
            acc[s][3] = __builtin_amdgcn_mfma_f32_16x16x32_bf16(a[2], b10, acc[s][3], 0, 0, 0);
            acc[s][3] = __builtin_amdgcn_mfma_f32_16x16x32_bf16(a[6], b01, acc[s][3], 0, 0, 0);
            acc[s][3] = __builtin_amdgcn_mfma_f32_16x16x32_bf16(a[8], b00, acc[s][3], 0, 0, 0);
        }
    }

    const float4 bv = *(const float4*)&bias[co0 + quad * 4];
    const float bb[4] = {bv.x, bv.y, bv.z, bv.w};
    const int x = x0 + n16;

    if (!OUT_NCHW) {
        unsigned short* outN = out + (size_t)img * OH * OW * COUT;
#pragma unroll
        for (int s = 0; s < 4; s++) {
            const int y = y0 + s;
#pragma unroll
            for (int c = 0; c < 4; c++) {
                const int oy = 2 * y + (c >> 1);
                const int ox = 2 * x + (c & 1);
                ushort4 h;
                h.x = f2bf(fmaxf(acc[s][c][0] + bb[0], 0.f));
                h.y = f2bf(fmaxf(acc[s][c][1] + bb[1], 0.f));
                h.z = f2bf(fmaxf(acc[s][c][2] + bb[2], 0.f));
                h.w = f2bf(fmaxf(acc[s][c][3] + bb[3], 0.f));
                *(ushort4*)(outN + ((size_t)(oy * OW + ox) * COUT + co0 + quad * 4)) = h;
            }
        }
    } else {
#pragma unroll
        for (int s = 0; s < 4; s++) {
            const int y = y0 + s;
#pragma unroll
            for (int r = 0; r < 4; r++) {
                const int co = co0 + quad * 4 + r;
                unsigned short* oC = out + (size_t)(img * COUT + co) * OH * OW;
                unsigned p0 = (unsigned)f2bf(fmaxf(acc[s][0][r] + bb[r], 0.f)) |
                              ((unsigned)f2bf(fmaxf(acc[s][1][r] + bb[r], 0.f)) << 16);
                unsigned p1 = (unsigned)f2bf(fmaxf(acc[s][2][r] + bb[r], 0.f)) |
                              ((unsigned)f2bf(fmaxf(acc[s][3][r] + bb[r], 0.f)) << 16);
                *(unsigned*)(oC + (size_t)(2 * y) * OW + 2 * x) = p0;
                *(unsigned*)(oC + (size_t)(2 * y + 1) * OW + 2 * x) = p1;
            }
        }
    }
}

// ---------------------------------------------------------------------------
// Final conv 64->3 + sigmoid. NCHW bf16 input, fp32 out (d_out).
// ---------------------------------------------------------------------------
__global__ __launch_bounds__(256)
void conv_out_kernel(const unsigned short* __restrict__ in, // [16,64,256,256] bf16
                     const float* __restrict__ w,           // [3,64,3,3]
                     const float* __restrict__ bias,
                     float* __restrict__ out)               // [16,3,256,256]
{
    constexpr int TIC = 4;
    __shared__ float s_in[TIC][3][258];
    const int t = threadIdx.x;
    const int y = blockIdx.x;
    const int n = blockIdx.y;
    const unsigned short* inN = in + (size_t)n * 64 * 65536;
    float acc0 = bias[0], acc1 = bias[1], acc2 = bias[2];

    for (int c0 = 0; c0 < 64; c0 += TIC) {
        for (int e = t; e < TIC * 3 * 258; e += 256) {
            int ci = e / 774;
            int r  = e % 774;
            int ry = r / 258, xx = r % 258;
            int gy = y - 1 + ry, gx = xx - 1;
            float v = 0.f;
            if ((unsigned)gy < 256u && (unsigned)gx < 256u)
                v = bf2f(inN[(size_t)(c0 + ci) * 65536 + gy * 256 + gx]);
            s_in[ci][ry][xx] = v;
        }
        __syncthreads();
#pragma unroll
        for (int ci = 0; ci < TIC; ++ci) {
            float iv[3][3];
#pragma unroll
            for (int ry = 0; ry < 3; ry++)
#pragma unroll
                for (int kx = 0; kx < 3; kx++)
                    iv[ry][kx] = s_in[ci][ry][t + kx];
#pragma unroll
            for (int k = 0; k < 9; k++) {
                const float v = iv[k / 3][k % 3];
                acc0 += w[(0 * 64 + c0 + ci) * 9 + k] * v;
                acc1 += w[(1 * 64 + c0 + ci) * 9 + k] * v;
                acc2 += w[(2 * 64 + c0 + ci) * 9 + k] * v;
            }
        }
        __syncthreads();
    }
    const size_t o = (size_t)((n * 3 + 0) * 256 + y) * 256 + t;
    out[o]          = 1.f / (1.f + __expf(-acc0));
    out[o + 65536]  = 1.f / (1.f + __expf(-acc1));
    out[o + 131072] = 1.f / (1.f + __expf(-acc2));
}

// ---------------------------------------------------------------------------
// Workspace (peak 201.5 MB) — same layout as round 6.
// d_out head scratch: EW3h/l, EW4h/l, WP1-3, EW2h/l (all < 9.3 MB,
// overwritten by conv_out; idxf at byte 12.58M untouched by scratch).
// ---------------------------------------------------------------------------
extern "C" void kernel_launch(void* const* d_in, const int* in_sizes, int n_in,
                              void* d_out, int out_size, void* d_ws, size_t ws_size,
                              hipStream_t stream)
{
    const float* x   = (const float*)d_in[0];
    const float* w1  = (const float*)d_in[1];
    const float* b1  = (const float*)d_in[2];
    const float* w2  = (const float*)d_in[3];
    const float* b2  = (const float*)d_in[4];
    const float* w3  = (const float*)d_in[5];
    const float* b3  = (const float*)d_in[6];
    const float* w4  = (const float*)d_in[7];
    const float* b4  = (const float*)d_in[8];
    const float* cb  = (const float*)d_in[9];
    const float* d1w = (const float*)d_in[10];
    const float* d1b = (const float*)d_in[11];
    const float* d2w = (const float*)d_in[12];
    const float* d2b = (const float*)d_in[13];
    const float* d3w = (const float*)d_in[14];
    const float* d3b = (const float*)d_in[15];
    const float* wo  = (const float*)d_in[16];
    const float* bo  = (const float*)d_in[17];

    char* ws = (char*)d_ws;
    _Float16* H2H = (_Float16*)(ws);
    _Float16* H2L = (_Float16*)(ws + 67108864);
    _Float16* H3H = (_Float16*)(ws + 134217728);
    _Float16* H3L = (_Float16*)(ws + 167772160);
    _Float16* ZH  = (_Float16*)(ws);
    _Float16* ZL  = (_Float16*)(ws + 16777216);
    unsigned short* ZQ = (unsigned short*)(ws + 33554432);
    _Float16* CBH = (_Float16*)(ws + 50331648);
    _Float16* CBL = (_Float16*)(ws + 58720256);
    unsigned short* G1 = (unsigned short*)(ws + 67108864);
    unsigned short* G2 = (unsigned short*)(ws + 134217728);
    unsigned short* G3 = (unsigned short*)(ws);
    unsigned long long* keys = (unsigned long long*)(ws + 201326592);
    float* cn = (float*)(ws + 201326592 + 131072);

    char* oscratch = (char*)d_out;
    _Float16* EW3H = (_Float16*)(oscratch);
    _Float16* EW3L = (_Float16*)(oscratch + 589824);
    _Float16* EW4H = (_Float16*)(oscratch + 1179648);
    _Float16* EW4L = (_Float16*)(oscratch + 3538944);
    unsigned short* WP1 = (unsigned short*)(oscratch + 5898240);
    unsigned short* WP2 = (unsigned short*)(oscratch + 8257536);
    unsigned short* WP3 = (unsigned short*)(oscratch + 8847360);
    _Float16* EW2H = (_Float16*)(oscratch + 8994816);
    _Float16* EW2L = (_Float16*)(oscratch + 9142272);

    float* xrec = (float*)d_out;
    float* idxf = (float*)d_out + (size_t)16 * 3 * 256 * 256;

    // ---- weight prepacks ----
    prepack_conv_kernel<64,  128><<<288,  256, 0, stream>>>(w2, EW2H, EW2L);
    prepack_conv_kernel<128, 256><<<1152, 256, 0, stream>>>(w3, EW3H, EW3L);
    prepack_conv_kernel<256, 512><<<4608, 256, 0, stream>>>(w4, EW4H, EW4L);
    prepack_kernel<512, 256><<<4608, 256, 0, stream>>>(d1w, WP1);
    prepack_kernel<256, 128><<<1152, 256, 0, stream>>>(d2w, WP2);
    prepack_kernel<128, 64 ><<<288,  256, 0, stream>>>(d3w, WP3);

    // ---- encoder ----
    fused_conv12_mfma_kernel<<<dim3(256, 2, 16), 256, 0, stream>>>(x, w1, b1, EW2H, EW2L, b2, H2H, H2L);
    conv_mfma_kernel<128, 256, 128, 128, true ><<<dim3(64, 4, 16), 256, 0, stream>>>(H2H, H2L, EW3H, EW3L, b3, H3H, H3L);
    conv_mfma_kernel<256, 512, 64,  64,  false><<<dim3(16, 8, 16), 256, 0, stream>>>(H3H, H3L, EW4H, EW4L, b4, ZH, ZL);

    // ---- VQ ----
    cnorm_kernel<<<8192, 64, 0, stream>>>(cb, cn);
    init_keys_kernel<<<64, 256, 0, stream>>>(keys);
    split_cb_kernel<<<16384, 256, 0, stream>>>(cb, CBH, CBL);
    vq_mfma_kernel<<<dim3(128, 64), 256, 0, stream>>>(ZH, ZL, CBH, CBL, cn, keys);
    vq_gather_kernel<<<256, 256, 0, stream>>>(keys, cb, ZQ, idxf);

    // ---- decoder (bf16 MFMA) ----
    deconv_mfma_kernel<512, 256, 32,  32,  false><<<dim3(16,  4, 16), 256, 0, stream>>>(ZQ, WP1, d1b, G1);
    deconv_mfma_kernel<256, 128, 64,  64,  false><<<dim3(64,  2, 16), 256, 0, stream>>>(G1, WP2, d2b, G2);
    deconv_mfma_kernel<128, 64,  128, 128, true ><<<dim3(256, 1, 16), 256, 0, stream>>>(G2, WP3, d3b, G3);
    conv_out_kernel<<<dim3(256, 16), 256, 0, stream>>>(G3, wo, bo, xrec);
}